// Round 9
// baseline (306.271 us; speedup 1.0000x reference)
//
#include <hip/hip_runtime.h>

#define B_ 2
#define L_ 2048
#define D_ 1024
#define H_ 16
#define DH_ 64

typedef float f32x4 __attribute__((ext_vector_type(4)));
typedef __bf16 bf16x8 __attribute__((ext_vector_type(8)));

__device__ __forceinline__ ushort f2bf(float f) {
  unsigned u = __float_as_uint(f);
  u += 0x7fffu + ((u >> 16) & 1u);
  return (ushort)(u >> 16);
}
__device__ __forceinline__ float bf2f(ushort h) {
  return __uint_as_float(((unsigned)h) << 16);
}

__device__ __forceinline__ void gload_lds16(const void* g, void* l) {
  __builtin_amdgcn_global_load_lds(
      (const __attribute__((address_space(1))) unsigned*)g,
      (__attribute__((address_space(3))) unsigned*)l, 16, 0, 0);
}

// ---------------- cast f32 -> bf16, all four weights in one launch ----------------
__global__ __launch_bounds__(256) void cast_all_kernel(const float* __restrict__ w0,
                                                       const float* __restrict__ w1,
                                                       const float* __restrict__ w2,
                                                       const float* __restrict__ w3,
                                                       ushort* __restrict__ o0,
                                                       ushort* __restrict__ o1,
                                                       ushort* __restrict__ o2,
                                                       ushort* __restrict__ o3) {
  int i = blockIdx.x * 256 + threadIdx.x;
  const float* src;
  ushort* dst;
  int j = i;
  if (j < 786432) { src = w0; dst = o0; }
  else if (j < 786432 + 262144) { j -= 786432; src = w1; dst = o1; }
  else if (j < 786432 + 262144 + 1048576) { j -= 786432 + 262144; src = w2; dst = o2; }
  else { j -= 786432 + 262144 + 1048576; src = w3; dst = o3; }
  float4 v = ((const float4*)src)[j];
  ushort4 o;
  o.x = f2bf(v.x); o.y = f2bf(v.y); o.z = f2bf(v.z); o.w = f2bf(v.w);
  ((ushort4*)dst)[j] = o;
}

// ---------------- RMSNorm (T in, bf16 out), one block per row of 1024 ----------------
template <typename T>
__global__ __launch_bounds__(256) void rmsnorm_kernel(const T* __restrict__ x,
                                                      const float* __restrict__ scale,
                                                      ushort* __restrict__ out) {
  int row = blockIdx.x, t = threadIdx.x;
  float4 v;
  if constexpr (sizeof(T) == 4) {
    v = ((const float4*)((const float*)x + (size_t)row * D_))[t];
  } else {
    ushort4 u = ((const ushort4*)((const ushort*)x + (size_t)row * D_))[t];
    v.x = bf2f(u.x); v.y = bf2f(u.y); v.z = bf2f(u.z); v.w = bf2f(u.w);
  }
  float ss = v.x * v.x + v.y * v.y + v.z * v.z + v.w * v.w;
#pragma unroll
  for (int d = 1; d < 64; d <<= 1) ss += __shfl_xor(ss, d);
  __shared__ float wsum[4];
  if ((t & 63) == 0) wsum[t >> 6] = ss;
  __syncthreads();
  float tot = wsum[0] + wsum[1] + wsum[2] + wsum[3];
  float r = rsqrtf(tot * (1.0f / D_) + 1e-6f);
  float4 sc = ((const float4*)scale)[t];
  ushort4 o;
  o.x = f2bf(v.x * sc.x * r); o.y = f2bf(v.y * sc.y * r);
  o.z = f2bf(v.z * sc.z * r); o.w = f2bf(v.w * sc.w * r);
  ((ushort4*)(out + (size_t)row * D_))[t] = o;
}

// ---------------- NT GEMM: C[m][n] = sum_k A[m][k]*Bw[n][k]  (bf16 in, fp32 acc) ---------
// Ring-buffered LDS pipeline (DEPTH deep), raw s_barrier + counted vmcnt ladder.
// LDS chunk-XOR swizzle via pre-swizzled gload source (conflict-free).
// 128x128 tile everywhere: each wave owns 64x64 -> 16 MFMA per 8KB LDS read
// (32 FLOP/LDS-byte; the 64x64-tile variant was LDS-BW bound at 16 FLOP/byte).
// XCD chunking: XR x XC rect per XCD; CTFAST picks which operand slice stays hot in L2.
// EPI 0: bf16 acc. EPI 1: bf16 (residf32+acc). EPI 2: bf16 gelu(acc).
// EPI 3: f32 (residbf16+acc).
template <int EPI, int BM, int BN, int DEPTH, int XR, int XC, bool CTFAST>
__global__ __launch_bounds__(256) void gemm_nt(const ushort* __restrict__ A,
                                               const ushort* __restrict__ Bw,
                                               void* __restrict__ Cout,
                                               const void* __restrict__ resid,
                                               int M, int N, int K) {
  constexpr int WROWS = BM / 2, WCOLS = BN / 2;
  constexpr int MR = WROWS / 16, NR = WCOLS / 16;
  constexpr int ALOADS = BM / 64, BLOADS = BN / 64;
  constexpr int NLOADS = ALOADS + BLOADS;
  __shared__ __align__(16) ushort Als[DEPTH][BM * 32];
  __shared__ __align__(16) ushort Bls[DEPTH][BN * 32];
  const int tid = threadIdx.x;
  const int lane = tid & 63;
  const int w = tid >> 6;
  const int wr = w >> 1, wc = w & 1;
  const int bid = blockIdx.y * gridDim.x + blockIdx.x;
  const int xcd = bid & 7;
  const int i0 = bid >> 3;
  const int CR = gridDim.x / XR, CC = gridDim.y / XC;
  int rt, ct;
  if constexpr (CTFAST) {
    rt = (xcd % XR) * CR + (i0 / CC);
    ct = (xcd / XR) * CC + (i0 % CC);
  } else {
    rt = (xcd % XR) * CR + (i0 % CR);
    ct = (xcd / XR) * CC + (i0 / CR);
  }
  const int row0 = rt * BM;
  const int col0 = ct * BN;
  const ushort* Ab = A + (size_t)row0 * K;
  const ushort* Bb = Bw + (size_t)col0 * K;
  const int sr = tid >> 2;  // staging row 0..63
  const int scA = (((tid & 3) ^ ((tid >> 3) & 3)) * 8);  // inverse-swizzled source chunk
  const int fr = lane & 15;
  const int fg = lane >> 4;
  f32x4 zero = {0.f, 0.f, 0.f, 0.f};
  f32x4 acc[MR][NR];
#pragma unroll
  for (int m = 0; m < MR; m++)
#pragma unroll
    for (int n = 0; n < NR; n++) acc[m][n] = zero;

  auto stage = [&](int slot, int kt) {
#pragma unroll
    for (int i2 = 0; i2 < ALOADS; i2++)
      gload_lds16(Ab + (size_t)(sr + 64 * i2) * K + kt + scA, &Als[slot][i2 * 2048 + tid * 8]);
#pragma unroll
    for (int i2 = 0; i2 < BLOADS; i2++)
      gload_lds16(Bb + (size_t)(sr + 64 * i2) * K + kt + scA, &Bls[slot][i2 * 2048 + tid * 8]);
  };
  const int nt = K >> 5;
#pragma unroll
  for (int p = 0; p < DEPTH - 1; p++) stage(p, p << 5);
  int cur = 0, sbuf = DEPTH - 1;
  for (int t = 0; t < nt; t++) {
    const int ahead = nt - 1 - t;
    if constexpr (DEPTH == 3) {
      if (ahead >= 1) asm volatile("s_waitcnt vmcnt(%0)" ::"i"(NLOADS) : "memory");
      else            asm volatile("s_waitcnt vmcnt(0)" ::: "memory");
    } else {  // DEPTH == 5
      if (ahead >= 3)      asm volatile("s_waitcnt vmcnt(%0)" ::"i"(3 * NLOADS) : "memory");
      else if (ahead == 2) asm volatile("s_waitcnt vmcnt(%0)" ::"i"(2 * NLOADS) : "memory");
      else if (ahead == 1) asm volatile("s_waitcnt vmcnt(%0)" ::"i"(NLOADS) : "memory");
      else                 asm volatile("s_waitcnt vmcnt(0)" ::: "memory");
    }
    __builtin_amdgcn_s_barrier();
    __builtin_amdgcn_sched_barrier(0);
    if (t + DEPTH - 1 < nt) {
      stage(sbuf, (t + DEPTH - 1) << 5);
      sbuf = (sbuf == DEPTH - 1) ? 0 : sbuf + 1;
    }
    bf16x8 af[MR], bfr[NR];
#pragma unroll
    for (int m = 0; m < MR; m++) {
      int rA = wr * WROWS + m * 16 + fr;
      af[m] = *(const bf16x8*)&Als[cur][rA * 32 + ((fg ^ ((rA >> 1) & 3)) << 3)];
    }
#pragma unroll
    for (int n = 0; n < NR; n++) {
      int rB = wc * WCOLS + n * 16 + fr;
      bfr[n] = *(const bf16x8*)&Bls[cur][rB * 32 + ((fg ^ ((rB >> 1) & 3)) << 3)];
    }
    __builtin_amdgcn_s_setprio(1);
#pragma unroll
    for (int m = 0; m < MR; m++)
#pragma unroll
      for (int n = 0; n < NR; n++)
        acc[m][n] = __builtin_amdgcn_mfma_f32_16x16x32_bf16(af[m], bfr[n], acc[m][n], 0, 0, 0);
    __builtin_amdgcn_s_setprio(0);
    cur = (cur == DEPTH - 1) ? 0 : cur + 1;
  }
  const int orow = row0 + wr * WROWS + fg * 4;
  const int ocol = col0 + wc * WCOLS + fr;
#pragma unroll
  for (int m = 0; m < MR; m++) {
#pragma unroll
    for (int j = 0; j < 4; j++) {
      int r = orow + m * 16 + j;
#pragma unroll
      for (int n = 0; n < NR; n++) {
        int cidx = ocol + n * 16;
        size_t idx = (size_t)r * N + cidx;
        float v = acc[m][n][j];
        if (EPI == 0) {
          ((ushort*)Cout)[idx] = f2bf(v);
        } else if (EPI == 1) {
          ((ushort*)Cout)[idx] = f2bf(((const float*)resid)[idx] + v);
        } else if (EPI == 2) {
          float g = 0.5f * v * (1.0f + tanhf(0.7978845608f * (v + 0.044715f * v * v * v)));
          ((ushort*)Cout)[idx] = f2bf(g);
        } else {
          ((float*)Cout)[idx] = bf2f(((const ushort*)resid)[idx]) + v;
        }
      }
    }
  }
}

// ---------------- RoPE + cosine-sim scaling. One wave per (b,l,h); lane = dh -------------
__global__ __launch_bounds__(256) void rope_kernel(const ushort* __restrict__ qkv,
                                                   const float* __restrict__ pos,
                                                   const float* __restrict__ pos_orig,
                                                   const float* __restrict__ timep,
                                                   const float* __restrict__ qk_scale,
                                                   ushort* __restrict__ qr,
                                                   ushort* __restrict__ kr) {
  int gw = (blockIdx.x * 256 + threadIdx.x) >> 6;  // (b*L + l)*H + h
  int lane = threadIdx.x & 63;
  int h = gw & 15;
  int row = gw >> 4;           // b*L + l
  int b = row >> 11;           // / L_
  int l = row & (L_ - 1);
  float qv = bf2f(qkv[(size_t)row * 3072 + h * 64 + lane]);
  float kv = bf2f(qkv[(size_t)row * 3072 + 1024 + h * 64 + lane]);
  float c = 1.0f, s = 0.0f;
  if (lane < 50) {
    int idx = lane < 25 ? lane : lane - 25;
    int sg = idx / 5, d = idx % 5;
    int fi = d * 16 + h;
    float th;
    if (sg == 4) {
      th = timep[row] * __expf(-(float)fi * 0.05756462732485115f);
    } else {
      float fr = 3.14159265358979323846f * __expf((float)fi * 0.028782313662425575f);
      const float* psrc = (sg == 0 || sg == 2) ? pos_orig : pos;
      int comp = (sg < 2) ? 1 : 0;
      th = (2.0f * psrc[(size_t)row * 2 + comp] - 1.0f) * fr;
    }
    s = sinf(th);
    c = cosf(th);
  }
  int partner = lane < 25 ? lane + 25 : lane - 25;
  float qp = __shfl(qv, partner, 64);
  float kp = __shfl(kv, partner, 64);
  float yq, yk;
  if (lane < 25) { yq = qv * c - qp * s; yk = kv * c - kp * s; }
  else if (lane < 50) { yq = qv * c + qp * s; yk = kv * c + kp * s; }
  else { yq = qv; yk = kv; }
  float sq = yq * yq, sk = yk * yk;
#pragma unroll
  for (int d = 1; d < 64; d <<= 1) { sq += __shfl_xor(sq, d); sk += __shfl_xor(sk, d); }
  float scl = sqrtf(qk_scale[h]);
  float qo = yq * scl * rsqrtf(sq + 1e-6f);
  float ko = yk * scl * rsqrtf(sk + 1e-6f);
  size_t o = ((size_t)(b * 16 + h) * L_ + l) * 64 + lane;
  qr[o] = f2bf(qo);
  kr[o] = f2bf(ko);
}

// ---------------- V transpose: qkv v-slice (b,l,h,dh) -> vT (b,h,dh,l) ----------------
__global__ __launch_bounds__(256) void vtrans_kernel(const ushort* __restrict__ qkv,
                                                     ushort* __restrict__ vT) {
  __shared__ __align__(16) ushort tile[64][72];
  int t = threadIdx.x;
  int lt = blockIdx.x;  // l tile of 64
  int bh = blockIdx.y;
  int b = bh >> 4, h = bh & 15;
  int r = t >> 3, c0 = (t & 7) * 8;
#pragma unroll
  for (int half = 0; half < 2; half++) {
    const ushort* src =
        qkv + (size_t)(b * L_ + lt * 64 + r + half * 32) * 3072 + 2048 + h * 64 + c0;
    *(uint4*)&tile[r + half * 32][c0] = *(const uint4*)src;
  }
  __syncthreads();
#pragma unroll
  for (int half = 0; half < 2; half++) {
    int dh = r + half * 32;
    unsigned p0 = (unsigned)tile[c0 + 0][dh] | ((unsigned)tile[c0 + 1][dh] << 16);
    unsigned p1 = (unsigned)tile[c0 + 2][dh] | ((unsigned)tile[c0 + 3][dh] << 16);
    unsigned p2 = (unsigned)tile[c0 + 4][dh] | ((unsigned)tile[c0 + 5][dh] << 16);
    unsigned p3 = (unsigned)tile[c0 + 6][dh] | ((unsigned)tile[c0 + 7][dh] << 16);
    uint4 o; o.x = p0; o.y = p1; o.z = p2; o.w = p3;
    *(uint4*)&vT[((size_t)bh * 64 + dh) * L_ + lt * 64 + c0] = o;
  }
}

// ---------------- Flash attention, 64x64 tiles, 4 waves x 16 q-rows -------------------
// Constant-max softmax; double-buffered K/V; raw s_barrier + vmcnt(0) of loads issued
// one tile earlier; XCD-locality remap (each XCD owns 4 heads, 2MB L2-resident K/V).
__global__ __launch_bounds__(256) void attn_kernel(const ushort* __restrict__ qr,
                                                   const ushort* __restrict__ kr,
                                                   const ushort* __restrict__ vT,
                                                   ushort* __restrict__ attnb) {
  __shared__ __align__(16) ushort Kls[2][64 * 64];
  __shared__ __align__(16) ushort Vls[2][64 * 64];
  __shared__ __align__(16) ushort Pls[4][16 * 64];
  const int tid = threadIdx.x, lane = tid & 63, w = tid >> 6;
  const int bid = blockIdx.y * gridDim.x + blockIdx.x;
  const int qt = (bid >> 3) & 31;
  const int bh = (bid & 7) | ((bid >> 8) << 3);
  const int b = bh >> 4;
  const int fr = lane & 15, fg = lane >> 4;
  const ushort* Qb = qr + ((size_t)bh * L_ + qt * 64 + w * 16) * 64;
  bf16x8 qf[2];
#pragma unroll
  for (int c = 0; c < 2; c++)
    qf[c] = *(const bf16x8*)(Qb + fr * 64 + c * 32 + fg * 8);
  f32x4 zero = {0.f, 0.f, 0.f, 0.f};
  f32x4 accO[4];
#pragma unroll
  for (int n = 0; n < 4; n++) accO[n] = zero;
  float lrow[4] = {0.f, 0.f, 0.f, 0.f};
  const int sr = tid >> 3;
  const int scz = (((tid & 7) ^ (sr & 7)) * 8);
  auto stage = [&](int buf, int kt) {
    gload_lds16(kr + ((size_t)bh * L_ + kt + sr) * 64 + scz, &Kls[buf][tid * 8]);
    gload_lds16(kr + ((size_t)bh * L_ + kt + 32 + sr) * 64 + scz, &Kls[buf][2048 + tid * 8]);
    gload_lds16(vT + ((size_t)bh * 64 + sr) * L_ + kt + scz, &Vls[buf][tid * 8]);
    gload_lds16(vT + ((size_t)bh * 64 + 32 + sr) * L_ + kt + scz, &Vls[buf][2048 + tid * 8]);
  };
  stage(0, 0);
  int cur = 0;
  for (int t = 0; t < (L_ >> 6); t++) {
    asm volatile("s_waitcnt vmcnt(0)" ::: "memory");
    __builtin_amdgcn_s_barrier();
    __builtin_amdgcn_sched_barrier(0);
    if (t + 1 < (L_ >> 6)) stage(cur ^ 1, (t + 1) << 6);
    f32x4 sv[4];
#pragma unroll
    for (int n = 0; n < 4; n++) sv[n] = zero;
    __builtin_amdgcn_s_setprio(1);
#pragma unroll
    for (int c = 0; c < 2; c++) {
#pragma unroll
      for (int n = 0; n < 4; n++) {
        bf16x8 kf =
            *(const bf16x8*)&Kls[cur][(n * 16 + fr) * 64 + (((c * 4 + fg) ^ (fr & 7)) << 3)];
        sv[n] = __builtin_amdgcn_mfma_f32_16x16x32_bf16(qf[c], kf, sv[n], 0, 0, 0);
      }
    }
    __builtin_amdgcn_s_setprio(0);
#pragma unroll
    for (int n = 0; n < 4; n++)
#pragma unroll
      for (int j = 0; j < 4; j++) {
        float p = __expf(sv[n][j] - 12.0f);
        sv[n][j] = p;
        lrow[j] += p;
      }
#pragma unroll
    for (int j = 0; j < 4; j++) {
      int row = fg * 4 + j;
      int rbase = row * 64;
      int rx = row & 7;
#pragma unroll
      for (int n = 0; n < 4; n++) {
        int chunk = 2 * n + (fr >> 3);
        Pls[w][rbase + ((chunk ^ rx) << 3) + (fr & 7)] =
            (ushort)(__float_as_uint(sv[n][j]) >> 16);
      }
    }
    __builtin_amdgcn_s_setprio(1);
#pragma unroll
    for (int c = 0; c < 2; c++) {
      bf16x8 pa = *(const bf16x8*)&Pls[w][fr * 64 + (((c * 4 + fg) ^ (fr & 7)) << 3)];
#pragma unroll
      for (int n = 0; n < 4; n++) {
        bf16x8 vb =
            *(const bf16x8*)&Vls[cur][(n * 16 + fr) * 64 + (((c * 4 + fg) ^ (fr & 7)) << 3)];
        accO[n] = __builtin_amdgcn_mfma_f32_16x16x32_bf16(pa, vb, accO[n], 0, 0, 0);
      }
    }
    __builtin_amdgcn_s_setprio(0);
    cur ^= 1;
  }
#pragma unroll
  for (int j = 0; j < 4; j++) {
#pragma unroll
    for (int d = 1; d < 16; d <<= 1) lrow[j] += __shfl_xor(lrow[j], d);
    lrow[j] = 1.0f / lrow[j];
  }
#pragma unroll
  for (int n = 0; n < 4; n++) {
#pragma unroll
    for (int j = 0; j < 4; j++) {
      float o = accO[n][j] * lrow[j];
      int qrow = qt * 64 + w * 16 + fg * 4 + j;
      int dh = fr + n * 16;
      attnb[(size_t)(b * L_ + qrow) * 1024 + (bh & 15) * 64 + dh] = f2bf(o);
    }
  }
}

extern "C" void kernel_launch(void* const* d_in, const int* in_sizes, int n_in,
                              void* d_out, int out_size, void* d_ws, size_t ws_size,
                              hipStream_t stream) {
  const float* x = (const float*)d_in[0];
  const float* pos = (const float*)d_in[1];
  const float* pos_orig = (const float*)d_in[2];
  const float* timep = (const float*)d_in[3];
  const float* w_qkv = (const float*)d_in[4];
  const float* w_out = (const float*)d_in[5];
  const float* w_up = (const float*)d_in[6];
  const float* w_down = (const float*)d_in[7];
  const float* norm1 = (const float*)d_in[8];
  const float* norm2 = (const float*)d_in[9];
  const float* qk_scale = (const float*)d_in[10];
  float* out = (float*)d_out;
  char* ws = (char*)d_ws;
  size_t off = 0;
  auto alloc = [&](size_t bytes) {
    void* p = ws + off;
    off += bytes;
    return p;
  };
  ushort* xn = (ushort*)alloc(8ull << 20);      // rmsnorm out, reused as h2
  ushort* qkvb = (ushort*)alloc(32ull << 20);   // qkv, reused as gelu-out g (32MB)
  ushort* qrb = (ushort*)alloc(8ull << 20);
  ushort* krb = (ushort*)alloc(8ull << 20);
  ushort* vTb = (ushort*)alloc(8ull << 20);
  ushort* attnb = (ushort*)alloc(8ull << 20);
  ushort* x1b = (ushort*)alloc(8ull << 20);     // bf16 residual x1
  ushort* wqkvb = (ushort*)alloc(6ull << 20);
  ushort* woutb = (ushort*)alloc(2ull << 20);
  ushort* wupb = (ushort*)alloc(8ull << 20);
  ushort* wdownb = (ushort*)alloc(8ull << 20);

  cast_all_kernel<<<12288, 256, 0, stream>>>(w_qkv, w_out, w_up, w_down,
                                             wqkvb, woutb, wupb, wdownb);

  rmsnorm_kernel<float><<<4096, 256, 0, stream>>>(x, norm1, xn);
  // qkv: 128x128 depth3, rt-fastest (A-slice 2MB resident)
  gemm_nt<0, 128, 128, 3, 4, 2, false><<<dim3(32, 24), 256, 0, stream>>>(
      xn, wqkvb, qkvb, nullptr, 4096, 3072, 1024);
  rope_kernel<<<16384, 256, 0, stream>>>(qkvb, pos, pos_orig, timep, qk_scale, qrb, krb);
  vtrans_kernel<<<dim3(32, 32), 256, 0, stream>>>(qkvb, vTb);
  attn_kernel<<<dim3(32, 32), 256, 0, stream>>>(qrb, krb, vTb, attnb);
  // out: 128x128 depth5 (32 FLOP/LDS-byte), grid 32x8, rt-fastest
  gemm_nt<1, 128, 128, 5, 4, 2, false><<<dim3(32, 8), 256, 0, stream>>>(
      attnb, woutb, x1b, x, 4096, 1024, 1024);
  rmsnorm_kernel<ushort><<<4096, 256, 0, stream>>>(x1b, norm2, xn);
  // up: 128x128 depth3, rt-fastest
  gemm_nt<2, 128, 128, 3, 4, 2, false><<<dim3(32, 32), 256, 0, stream>>>(
      xn, wupb, qkvb, nullptr, 4096, 4096, 1024);
  // down: 128x128 depth5, grid 32x8, ct-fastest (B-slice clustered, A streamed once)
  gemm_nt<3, 128, 128, 5, 4, 2, true><<<dim3(32, 8), 256, 0, stream>>>(
      qkvb, wdownb, out, x1b, 4096, 1024, 4096);
}

// Round 10
// 285.218 us; speedup vs baseline: 1.0738x; 1.0738x over previous
//
#include <hip/hip_runtime.h>

#define B_ 2
#define L_ 2048
#define D_ 1024
#define H_ 16
#define DH_ 64

typedef float f32x4 __attribute__((ext_vector_type(4)));
typedef __bf16 bf16x8 __attribute__((ext_vector_type(8)));

__device__ __forceinline__ ushort f2bf(float f) {
  unsigned u = __float_as_uint(f);
  u += 0x7fffu + ((u >> 16) & 1u);
  return (ushort)(u >> 16);
}
__device__ __forceinline__ float bf2f(ushort h) {
  return __uint_as_float(((unsigned)h) << 16);
}

__device__ __forceinline__ void gload_lds16(const void* g, void* l) {
  __builtin_amdgcn_global_load_lds(
      (const __attribute__((address_space(1))) unsigned*)g,
      (__attribute__((address_space(3))) unsigned*)l, 16, 0, 0);
}

// ---------------- cast f32 -> bf16, all four weights in one launch ----------------
__global__ __launch_bounds__(256) void cast_all_kernel(const float* __restrict__ w0,
                                                       const float* __restrict__ w1,
                                                       const float* __restrict__ w2,
                                                       const float* __restrict__ w3,
                                                       ushort* __restrict__ o0,
                                                       ushort* __restrict__ o1,
                                                       ushort* __restrict__ o2,
                                                       ushort* __restrict__ o3) {
  int i = blockIdx.x * 256 + threadIdx.x;
  const float* src;
  ushort* dst;
  int j = i;
  if (j < 786432) { src = w0; dst = o0; }
  else if (j < 786432 + 262144) { j -= 786432; src = w1; dst = o1; }
  else if (j < 786432 + 262144 + 1048576) { j -= 786432 + 262144; src = w2; dst = o2; }
  else { j -= 786432 + 262144 + 1048576; src = w3; dst = o3; }
  float4 v = ((const float4*)src)[j];
  ushort4 o;
  o.x = f2bf(v.x); o.y = f2bf(v.y); o.z = f2bf(v.z); o.w = f2bf(v.w);
  ((ushort4*)dst)[j] = o;
}

// ---------------- RMSNorm (T in, bf16 out), one block per row of 1024 ----------------
template <typename T>
__global__ __launch_bounds__(256) void rmsnorm_kernel(const T* __restrict__ x,
                                                      const float* __restrict__ scale,
                                                      ushort* __restrict__ out) {
  int row = blockIdx.x, t = threadIdx.x;
  float4 v;
  if constexpr (sizeof(T) == 4) {
    v = ((const float4*)((const float*)x + (size_t)row * D_))[t];
  } else {
    ushort4 u = ((const ushort4*)((const ushort*)x + (size_t)row * D_))[t];
    v.x = bf2f(u.x); v.y = bf2f(u.y); v.z = bf2f(u.z); v.w = bf2f(u.w);
  }
  float ss = v.x * v.x + v.y * v.y + v.z * v.z + v.w * v.w;
#pragma unroll
  for (int d = 1; d < 64; d <<= 1) ss += __shfl_xor(ss, d);
  __shared__ float wsum[4];
  if ((t & 63) == 0) wsum[t >> 6] = ss;
  __syncthreads();
  float tot = wsum[0] + wsum[1] + wsum[2] + wsum[3];
  float r = rsqrtf(tot * (1.0f / D_) + 1e-6f);
  float4 sc = ((const float4*)scale)[t];
  ushort4 o;
  o.x = f2bf(v.x * sc.x * r); o.y = f2bf(v.y * sc.y * r);
  o.z = f2bf(v.z * sc.z * r); o.w = f2bf(v.w * sc.w * r);
  ((ushort4*)(out + (size_t)row * D_))[t] = o;
}

// ---------------- NT GEMM: C[m][n] = sum_k A[m][k]*Bw[n][k]  (bf16 in, fp32 acc) ---------
// Ring-buffered LDS pipeline (DEPTH deep), raw s_barrier + counted vmcnt ladder.
// LDS chunk-XOR swizzle via pre-swizzled gload source (conflict-free).
// Klen: iteration length (<= K); split-K via gridDim.z: block z computes partial over
// [z*Klen, (z+1)*Klen) and stores f32 partial to Pk = Cout + z*M*N (EPI 4).
// XCD chunking: XR x XC rect per XCD; CTFAST picks which operand slice stays hot in L2.
// EPI 0: bf16 acc. EPI 1: bf16 (residf32+acc). EPI 2: bf16 gelu(acc).
// EPI 3: f32 (residbf16+acc). EPI 4: f32 raw acc partial at z-offset.
template <int EPI, int BM, int BN, int DEPTH, int XR, int XC, bool CTFAST>
__global__ __launch_bounds__(256) void gemm_nt(const ushort* __restrict__ A,
                                               const ushort* __restrict__ Bw,
                                               void* __restrict__ Cout,
                                               const void* __restrict__ resid,
                                               int M, int N, int K, int Klen) {
  constexpr int WROWS = BM / 2, WCOLS = BN / 2;
  constexpr int MR = WROWS / 16, NR = WCOLS / 16;
  constexpr int ALOADS = BM / 64, BLOADS = BN / 64;
  constexpr int NLOADS = ALOADS + BLOADS;
  __shared__ __align__(16) ushort Als[DEPTH][BM * 32];
  __shared__ __align__(16) ushort Bls[DEPTH][BN * 32];
  const int tid = threadIdx.x;
  const int lane = tid & 63;
  const int w = tid >> 6;
  const int wr = w >> 1, wc = w & 1;
  const int bid = blockIdx.y * gridDim.x + blockIdx.x;
  const int xcd = bid & 7;
  const int i0 = bid >> 3;
  const int CR = gridDim.x / XR, CC = gridDim.y / XC;
  int rt, ct;
  if constexpr (CTFAST) {
    rt = (xcd % XR) * CR + (i0 / CC);
    ct = (xcd / XR) * CC + (i0 % CC);
  } else {
    rt = (xcd % XR) * CR + (i0 % CR);
    ct = (xcd / XR) * CC + (i0 / CR);
  }
  const int row0 = rt * BM;
  const int col0 = ct * BN;
  const int koff = blockIdx.z * Klen;
  const ushort* Ab = A + (size_t)row0 * K + koff;
  const ushort* Bb = Bw + (size_t)col0 * K + koff;
  const int sr = tid >> 2;  // staging row 0..63
  const int scA = (((tid & 3) ^ ((tid >> 3) & 3)) * 8);  // inverse-swizzled source chunk
  const int fr = lane & 15;
  const int fg = lane >> 4;
  f32x4 zero = {0.f, 0.f, 0.f, 0.f};
  f32x4 acc[MR][NR];
#pragma unroll
  for (int m = 0; m < MR; m++)
#pragma unroll
    for (int n = 0; n < NR; n++) acc[m][n] = zero;

  auto stage = [&](int slot, int kt) {
#pragma unroll
    for (int i2 = 0; i2 < ALOADS; i2++)
      gload_lds16(Ab + (size_t)(sr + 64 * i2) * K + kt + scA, &Als[slot][i2 * 2048 + tid * 8]);
#pragma unroll
    for (int i2 = 0; i2 < BLOADS; i2++)
      gload_lds16(Bb + (size_t)(sr + 64 * i2) * K + kt + scA, &Bls[slot][i2 * 2048 + tid * 8]);
  };
  const int nt = Klen >> 5;
#pragma unroll
  for (int p = 0; p < DEPTH - 1; p++) stage(p, p << 5);
  int cur = 0, sbuf = DEPTH - 1;
  for (int t = 0; t < nt; t++) {
    const int ahead = nt - 1 - t;
    if constexpr (DEPTH == 3) {
      if (ahead >= 1) asm volatile("s_waitcnt vmcnt(%0)" ::"i"(NLOADS) : "memory");
      else            asm volatile("s_waitcnt vmcnt(0)" ::: "memory");
    } else {  // DEPTH == 5
      if (ahead >= 3)      asm volatile("s_waitcnt vmcnt(%0)" ::"i"(3 * NLOADS) : "memory");
      else if (ahead == 2) asm volatile("s_waitcnt vmcnt(%0)" ::"i"(2 * NLOADS) : "memory");
      else if (ahead == 1) asm volatile("s_waitcnt vmcnt(%0)" ::"i"(NLOADS) : "memory");
      else                 asm volatile("s_waitcnt vmcnt(0)" ::: "memory");
    }
    __builtin_amdgcn_s_barrier();
    __builtin_amdgcn_sched_barrier(0);
    if (t + DEPTH - 1 < nt) {
      stage(sbuf, (t + DEPTH - 1) << 5);
      sbuf = (sbuf == DEPTH - 1) ? 0 : sbuf + 1;
    }
    bf16x8 af[MR], bfr[NR];
#pragma unroll
    for (int m = 0; m < MR; m++) {
      int rA = wr * WROWS + m * 16 + fr;
      af[m] = *(const bf16x8*)&Als[cur][rA * 32 + ((fg ^ ((rA >> 1) & 3)) << 3)];
    }
#pragma unroll
    for (int n = 0; n < NR; n++) {
      int rB = wc * WCOLS + n * 16 + fr;
      bfr[n] = *(const bf16x8*)&Bls[cur][rB * 32 + ((fg ^ ((rB >> 1) & 3)) << 3)];
    }
    __builtin_amdgcn_s_setprio(1);
#pragma unroll
    for (int m = 0; m < MR; m++)
#pragma unroll
      for (int n = 0; n < NR; n++)
        acc[m][n] = __builtin_amdgcn_mfma_f32_16x16x32_bf16(af[m], bfr[n], acc[m][n], 0, 0, 0);
    __builtin_amdgcn_s_setprio(0);
    cur = (cur == DEPTH - 1) ? 0 : cur + 1;
  }
  const int orow = row0 + wr * WROWS + fg * 4;
  const int ocol = col0 + wc * WCOLS + fr;
  float* Pz = (float*)Cout + (size_t)blockIdx.z * M * N;
#pragma unroll
  for (int m = 0; m < MR; m++) {
#pragma unroll
    for (int j = 0; j < 4; j++) {
      int r = orow + m * 16 + j;
#pragma unroll
      for (int n = 0; n < NR; n++) {
        int cidx = ocol + n * 16;
        size_t idx = (size_t)r * N + cidx;
        float v = acc[m][n][j];
        if (EPI == 0) {
          ((ushort*)Cout)[idx] = f2bf(v);
        } else if (EPI == 1) {
          ((ushort*)Cout)[idx] = f2bf(((const float*)resid)[idx] + v);
        } else if (EPI == 2) {
          float g = 0.5f * v * (1.0f + tanhf(0.7978845608f * (v + 0.044715f * v * v * v)));
          ((ushort*)Cout)[idx] = f2bf(g);
        } else if (EPI == 3) {
          ((float*)Cout)[idx] = bf2f(((const ushort*)resid)[idx]) + v;
        } else {
          Pz[idx] = v;
        }
      }
    }
  }
}

// ---------------- split-K reduce: out = bf16resid + P0 + P1 (f32x4 lanes) --------------
__global__ __launch_bounds__(256) void reduce_down_kernel(const float* __restrict__ P0,
                                                          const float* __restrict__ P1,
                                                          const ushort* __restrict__ residb,
                                                          float* __restrict__ out) {
  int i = blockIdx.x * 256 + threadIdx.x;  // f32x4 index, 1M total
  float4 a = ((const float4*)P0)[i];
  float4 b = ((const float4*)P1)[i];
  ushort4 r = ((const ushort4*)residb)[i];
  float4 o;
  o.x = a.x + b.x + bf2f(r.x);
  o.y = a.y + b.y + bf2f(r.y);
  o.z = a.z + b.z + bf2f(r.z);
  o.w = a.w + b.w + bf2f(r.w);
  ((float4*)out)[i] = o;
}

// ---------------- RoPE + cosine-sim scaling. One wave per (b,l,h); lane = dh -------------
__global__ __launch_bounds__(256) void rope_kernel(const ushort* __restrict__ qkv,
                                                   const float* __restrict__ pos,
                                                   const float* __restrict__ pos_orig,
                                                   const float* __restrict__ timep,
                                                   const float* __restrict__ qk_scale,
                                                   ushort* __restrict__ qr,
                                                   ushort* __restrict__ kr) {
  int gw = (blockIdx.x * 256 + threadIdx.x) >> 6;  // (b*L + l)*H + h
  int lane = threadIdx.x & 63;
  int h = gw & 15;
  int row = gw >> 4;           // b*L + l
  int b = row >> 11;           // / L_
  int l = row & (L_ - 1);
  float qv = bf2f(qkv[(size_t)row * 3072 + h * 64 + lane]);
  float kv = bf2f(qkv[(size_t)row * 3072 + 1024 + h * 64 + lane]);
  float c = 1.0f, s = 0.0f;
  if (lane < 50) {
    int idx = lane < 25 ? lane : lane - 25;
    int sg = idx / 5, d = idx % 5;
    int fi = d * 16 + h;
    float th;
    if (sg == 4) {
      th = timep[row] * __expf(-(float)fi * 0.05756462732485115f);
    } else {
      float fr = 3.14159265358979323846f * __expf((float)fi * 0.028782313662425575f);
      const float* psrc = (sg == 0 || sg == 2) ? pos_orig : pos;
      int comp = (sg < 2) ? 1 : 0;
      th = (2.0f * psrc[(size_t)row * 2 + comp] - 1.0f) * fr;
    }
    s = sinf(th);
    c = cosf(th);
  }
  int partner = lane < 25 ? lane + 25 : lane - 25;
  float qp = __shfl(qv, partner, 64);
  float kp = __shfl(kv, partner, 64);
  float yq, yk;
  if (lane < 25) { yq = qv * c - qp * s; yk = kv * c - kp * s; }
  else if (lane < 50) { yq = qv * c + qp * s; yk = kv * c + kp * s; }
  else { yq = qv; yk = kv; }
  float sq = yq * yq, sk = yk * yk;
#pragma unroll
  for (int d = 1; d < 64; d <<= 1) { sq += __shfl_xor(sq, d); sk += __shfl_xor(sk, d); }
  float scl = sqrtf(qk_scale[h]);
  float qo = yq * scl * rsqrtf(sq + 1e-6f);
  float ko = yk * scl * rsqrtf(sk + 1e-6f);
  size_t o = ((size_t)(b * 16 + h) * L_ + l) * 64 + lane;
  qr[o] = f2bf(qo);
  kr[o] = f2bf(ko);
}

// ---------------- V transpose: qkv v-slice (b,l,h,dh) -> vT (b,h,dh,l) ----------------
__global__ __launch_bounds__(256) void vtrans_kernel(const ushort* __restrict__ qkv,
                                                     ushort* __restrict__ vT) {
  __shared__ __align__(16) ushort tile[64][72];
  int t = threadIdx.x;
  int lt = blockIdx.x;  // l tile of 64
  int bh = blockIdx.y;
  int b = bh >> 4, h = bh & 15;
  int r = t >> 3, c0 = (t & 7) * 8;
#pragma unroll
  for (int half = 0; half < 2; half++) {
    const ushort* src =
        qkv + (size_t)(b * L_ + lt * 64 + r + half * 32) * 3072 + 2048 + h * 64 + c0;
    *(uint4*)&tile[r + half * 32][c0] = *(const uint4*)src;
  }
  __syncthreads();
#pragma unroll
  for (int half = 0; half < 2; half++) {
    int dh = r + half * 32;
    unsigned p0 = (unsigned)tile[c0 + 0][dh] | ((unsigned)tile[c0 + 1][dh] << 16);
    unsigned p1 = (unsigned)tile[c0 + 2][dh] | ((unsigned)tile[c0 + 3][dh] << 16);
    unsigned p2 = (unsigned)tile[c0 + 4][dh] | ((unsigned)tile[c0 + 5][dh] << 16);
    unsigned p3 = (unsigned)tile[c0 + 6][dh] | ((unsigned)tile[c0 + 7][dh] << 16);
    uint4 o; o.x = p0; o.y = p1; o.z = p2; o.w = p3;
    *(uint4*)&vT[((size_t)bh * 64 + dh) * L_ + lt * 64 + c0] = o;
  }
}

// ---------------- Flash attention, 64x64 tiles, 4 waves x 16 q-rows -------------------
// Constant-max softmax; double-buffered K/V; raw s_barrier + vmcnt(0) of loads issued
// one tile earlier; XCD-locality remap (each XCD owns 4 heads, 2MB L2-resident K/V).
__global__ __launch_bounds__(256) void attn_kernel(const ushort* __restrict__ qr,
                                                   const ushort* __restrict__ kr,
                                                   const ushort* __restrict__ vT,
                                                   ushort* __restrict__ attnb) {
  __shared__ __align__(16) ushort Kls[2][64 * 64];
  __shared__ __align__(16) ushort Vls[2][64 * 64];
  __shared__ __align__(16) ushort Pls[4][16 * 64];
  const int tid = threadIdx.x, lane = tid & 63, w = tid >> 6;
  const int bid = blockIdx.y * gridDim.x + blockIdx.x;
  const int qt = (bid >> 3) & 31;
  const int bh = (bid & 7) | ((bid >> 8) << 3);
  const int b = bh >> 4;
  const int fr = lane & 15, fg = lane >> 4;
  const ushort* Qb = qr + ((size_t)bh * L_ + qt * 64 + w * 16) * 64;
  bf16x8 qf[2];
#pragma unroll
  for (int c = 0; c < 2; c++)
    qf[c] = *(const bf16x8*)(Qb + fr * 64 + c * 32 + fg * 8);
  f32x4 zero = {0.f, 0.f, 0.f, 0.f};
  f32x4 accO[4];
#pragma unroll
  for (int n = 0; n < 4; n++) accO[n] = zero;
  float lrow[4] = {0.f, 0.f, 0.f, 0.f};
  const int sr = tid >> 3;
  const int scz = (((tid & 7) ^ (sr & 7)) * 8);
  auto stage = [&](int buf, int kt) {
    gload_lds16(kr + ((size_t)bh * L_ + kt + sr) * 64 + scz, &Kls[buf][tid * 8]);
    gload_lds16(kr + ((size_t)bh * L_ + kt + 32 + sr) * 64 + scz, &Kls[buf][2048 + tid * 8]);
    gload_lds16(vT + ((size_t)bh * 64 + sr) * L_ + kt + scz, &Vls[buf][tid * 8]);
    gload_lds16(vT + ((size_t)bh * 64 + 32 + sr) * L_ + kt + scz, &Vls[buf][2048 + tid * 8]);
  };
  stage(0, 0);
  int cur = 0;
  for (int t = 0; t < (L_ >> 6); t++) {
    asm volatile("s_waitcnt vmcnt(0)" ::: "memory");
    __builtin_amdgcn_s_barrier();
    __builtin_amdgcn_sched_barrier(0);
    if (t + 1 < (L_ >> 6)) stage(cur ^ 1, (t + 1) << 6);
    f32x4 sv[4];
#pragma unroll
    for (int n = 0; n < 4; n++) sv[n] = zero;
    __builtin_amdgcn_s_setprio(1);
#pragma unroll
    for (int c = 0; c < 2; c++) {
#pragma unroll
      for (int n = 0; n < 4; n++) {
        bf16x8 kf =
            *(const bf16x8*)&Kls[cur][(n * 16 + fr) * 64 + (((c * 4 + fg) ^ (fr & 7)) << 3)];
        sv[n] = __builtin_amdgcn_mfma_f32_16x16x32_bf16(qf[c], kf, sv[n], 0, 0, 0);
      }
    }
    __builtin_amdgcn_s_setprio(0);
#pragma unroll
    for (int n = 0; n < 4; n++)
#pragma unroll
      for (int j = 0; j < 4; j++) {
        float p = __expf(sv[n][j] - 12.0f);
        sv[n][j] = p;
        lrow[j] += p;
      }
#pragma unroll
    for (int j = 0; j < 4; j++) {
      int row = fg * 4 + j;
      int rbase = row * 64;
      int rx = row & 7;
#pragma unroll
      for (int n = 0; n < 4; n++) {
        int chunk = 2 * n + (fr >> 3);
        Pls[w][rbase + ((chunk ^ rx) << 3) + (fr & 7)] =
            (ushort)(__float_as_uint(sv[n][j]) >> 16);
      }
    }
    __builtin_amdgcn_s_setprio(1);
#pragma unroll
    for (int c = 0; c < 2; c++) {
      bf16x8 pa = *(const bf16x8*)&Pls[w][fr * 64 + (((c * 4 + fg) ^ (fr & 7)) << 3)];
#pragma unroll
      for (int n = 0; n < 4; n++) {
        bf16x8 vb =
            *(const bf16x8*)&Vls[cur][(n * 16 + fr) * 64 + (((c * 4 + fg) ^ (fr & 7)) << 3)];
        accO[n] = __builtin_amdgcn_mfma_f32_16x16x32_bf16(pa, vb, accO[n], 0, 0, 0);
      }
    }
    __builtin_amdgcn_s_setprio(0);
    cur ^= 1;
  }
#pragma unroll
  for (int j = 0; j < 4; j++) {
#pragma unroll
    for (int d = 1; d < 16; d <<= 1) lrow[j] += __shfl_xor(lrow[j], d);
    lrow[j] = 1.0f / lrow[j];
  }
#pragma unroll
  for (int n = 0; n < 4; n++) {
#pragma unroll
    for (int j = 0; j < 4; j++) {
      float o = accO[n][j] * lrow[j];
      int qrow = qt * 64 + w * 16 + fg * 4 + j;
      int dh = fr + n * 16;
      attnb[(size_t)(b * L_ + qrow) * 1024 + (bh & 15) * 64 + dh] = f2bf(o);
    }
  }
}

extern "C" void kernel_launch(void* const* d_in, const int* in_sizes, int n_in,
                              void* d_out, int out_size, void* d_ws, size_t ws_size,
                              hipStream_t stream) {
  const float* x = (const float*)d_in[0];
  const float* pos = (const float*)d_in[1];
  const float* pos_orig = (const float*)d_in[2];
  const float* timep = (const float*)d_in[3];
  const float* w_qkv = (const float*)d_in[4];
  const float* w_out = (const float*)d_in[5];
  const float* w_up = (const float*)d_in[6];
  const float* w_down = (const float*)d_in[7];
  const float* norm1 = (const float*)d_in[8];
  const float* norm2 = (const float*)d_in[9];
  const float* qk_scale = (const float*)d_in[10];
  float* out = (float*)d_out;
  char* ws = (char*)d_ws;
  size_t off = 0;
  auto alloc = [&](size_t bytes) {
    void* p = ws + off;
    off += bytes;
    return p;
  };
  ushort* xn = (ushort*)alloc(8ull << 20);      // rmsnorm out, reused as h2
  ushort* qkvb = (ushort*)alloc(32ull << 20);   // qkv, reused as gelu-out g (32MB)
  ushort* qrb = (ushort*)alloc(8ull << 20);     // } qrb..attnb (32MB) reused as f32
  ushort* krb = (ushort*)alloc(8ull << 20);     // } split-K partials P0,P1 (16MB each)
  ushort* vTb = (ushort*)alloc(8ull << 20);     // } after attn/out-gemm complete
  ushort* attnb = (ushort*)alloc(8ull << 20);   // }
  ushort* x1b = (ushort*)alloc(8ull << 20);     // bf16 residual x1
  ushort* wqkvb = (ushort*)alloc(6ull << 20);
  ushort* woutb = (ushort*)alloc(2ull << 20);
  ushort* wupb = (ushort*)alloc(8ull << 20);
  ushort* wdownb = (ushort*)alloc(8ull << 20);
  float* Ppart = (float*)qrb;  // P0 = Ppart, P1 = Ppart + 4M floats

  cast_all_kernel<<<12288, 256, 0, stream>>>(w_qkv, w_out, w_up, w_down,
                                             wqkvb, woutb, wupb, wdownb);

  rmsnorm_kernel<float><<<4096, 256, 0, stream>>>(x, norm1, xn);
  // qkv: 128x128 depth3, rt-fastest (A-slice 2MB resident)
  gemm_nt<0, 128, 128, 3, 4, 2, false><<<dim3(32, 24), 256, 0, stream>>>(
      xn, wqkvb, qkvb, nullptr, 4096, 3072, 1024, 1024);
  rope_kernel<<<16384, 256, 0, stream>>>(qkvb, pos, pos_orig, timep, qk_scale, qrb, krb);
  vtrans_kernel<<<dim3(32, 32), 256, 0, stream>>>(qkvb, vTb);
  attn_kernel<<<dim3(32, 32), 256, 0, stream>>>(qrb, krb, vTb, attnb);
  // out: 64x64 depth5 grid(64,16) -- R7-proven config (2 blocks/CU)
  gemm_nt<1, 64, 64, 5, 4, 2, false><<<dim3(64, 16), 256, 0, stream>>>(
      attnb, woutb, x1b, x, 4096, 1024, 1024, 1024);
  rmsnorm_kernel<ushort><<<4096, 256, 0, stream>>>(x1b, norm2, xn);
  // up: 128x128 depth3, rt-fastest
  gemm_nt<2, 128, 128, 3, 4, 2, false><<<dim3(32, 32), 256, 0, stream>>>(
      xn, wupb, qkvb, nullptr, 4096, 4096, 1024, 1024);
  // down: split-K=2 in ONE dispatch (grid z=2 -> 512 blocks, 2/CU, depth3=48KB LDS);
  // z writes f32 partial at Ppart + z*4M; ct-fastest XCD map
  gemm_nt<4, 128, 128, 3, 4, 2, true><<<dim3(32, 8, 2), 256, 0, stream>>>(
      qkvb, wdownb, Ppart, nullptr, 4096, 1024, 4096, 2048);
  reduce_down_kernel<<<4096, 256, 0, stream>>>(Ppart, Ppart + (4u << 20), x1b, out);
}

// Round 11
// 285.087 us; speedup vs baseline: 1.0743x; 1.0005x over previous
//
#include <hip/hip_runtime.h>

#define B_ 2
#define L_ 2048
#define D_ 1024
#define H_ 16
#define DH_ 64

typedef float f32x4 __attribute__((ext_vector_type(4)));
typedef __bf16 bf16x8 __attribute__((ext_vector_type(8)));

__device__ __forceinline__ ushort f2bf(float f) {
  unsigned u = __float_as_uint(f);
  u += 0x7fffu + ((u >> 16) & 1u);
  return (ushort)(u >> 16);
}
__device__ __forceinline__ float bf2f(ushort h) {
  return __uint_as_float(((unsigned)h) << 16);
}

__device__ __forceinline__ void gload_lds16(const void* g, void* l) {
  __builtin_amdgcn_global_load_lds(
      (const __attribute__((address_space(1))) unsigned*)g,
      (__attribute__((address_space(3))) unsigned*)l, 16, 0, 0);
}

// ---------------- cast f32 -> bf16, all four weights in one launch ----------------
__global__ __launch_bounds__(256) void cast_all_kernel(const float* __restrict__ w0,
                                                       const float* __restrict__ w1,
                                                       const float* __restrict__ w2,
                                                       const float* __restrict__ w3,
                                                       ushort* __restrict__ o0,
                                                       ushort* __restrict__ o1,
                                                       ushort* __restrict__ o2,
                                                       ushort* __restrict__ o3) {
  int i = blockIdx.x * 256 + threadIdx.x;
  const float* src;
  ushort* dst;
  int j = i;
  if (j < 786432) { src = w0; dst = o0; }
  else if (j < 786432 + 262144) { j -= 786432; src = w1; dst = o1; }
  else if (j < 786432 + 262144 + 1048576) { j -= 786432 + 262144; src = w2; dst = o2; }
  else { j -= 786432 + 262144 + 1048576; src = w3; dst = o3; }
  float4 v = ((const float4*)src)[j];
  ushort4 o;
  o.x = f2bf(v.x); o.y = f2bf(v.y); o.z = f2bf(v.z); o.w = f2bf(v.w);
  ((ushort4*)dst)[j] = o;
}

// ---------------- RMSNorm (T in, bf16 out), one block per row of 1024 ----------------
template <typename T>
__global__ __launch_bounds__(256) void rmsnorm_kernel(const T* __restrict__ x,
                                                      const float* __restrict__ scale,
                                                      ushort* __restrict__ out) {
  int row = blockIdx.x, t = threadIdx.x;
  float4 v;
  if constexpr (sizeof(T) == 4) {
    v = ((const float4*)((const float*)x + (size_t)row * D_))[t];
  } else {
    ushort4 u = ((const ushort4*)((const ushort*)x + (size_t)row * D_))[t];
    v.x = bf2f(u.x); v.y = bf2f(u.y); v.z = bf2f(u.z); v.w = bf2f(u.w);
  }
  float ss = v.x * v.x + v.y * v.y + v.z * v.z + v.w * v.w;
#pragma unroll
  for (int d = 1; d < 64; d <<= 1) ss += __shfl_xor(ss, d);
  __shared__ float wsum[4];
  if ((t & 63) == 0) wsum[t >> 6] = ss;
  __syncthreads();
  float tot = wsum[0] + wsum[1] + wsum[2] + wsum[3];
  float r = rsqrtf(tot * (1.0f / D_) + 1e-6f);
  float4 sc = ((const float4*)scale)[t];
  ushort4 o;
  o.x = f2bf(v.x * sc.x * r); o.y = f2bf(v.y * sc.y * r);
  o.z = f2bf(v.z * sc.z * r); o.w = f2bf(v.w * sc.w * r);
  ((ushort4*)(out + (size_t)row * D_))[t] = o;
}

// ---------------- NT GEMM: C[m][n] = sum_k A[m][k]*Bw[n][k]  (bf16 in, fp32 acc) ---------
// Ring-buffered LDS pipeline (DEPTH deep), raw s_barrier + counted vmcnt ladder.
// LDS chunk-XOR swizzle via pre-swizzled gload source (conflict-free).
// Klen: iteration length (<= K); split-K via gridDim.z: block z computes partial over
// [z*Klen, (z+1)*Klen) and stores f32 partial to Pk = Cout + z*M*N (EPI 4).
// XCD chunking: XR x XC rect per XCD; CTFAST picks which operand slice stays hot in L2.
// EPI 0: bf16 acc. EPI 1: bf16 (residf32+acc). EPI 2: bf16 gelu(acc).
// EPI 3: f32 (residbf16+acc). EPI 4: f32 raw acc partial at z-offset.
template <int EPI, int BM, int BN, int DEPTH, int XR, int XC, bool CTFAST>
__global__ __launch_bounds__(256) void gemm_nt(const ushort* __restrict__ A,
                                               const ushort* __restrict__ Bw,
                                               void* __restrict__ Cout,
                                               const void* __restrict__ resid,
                                               int M, int N, int K, int Klen) {
  constexpr int WROWS = BM / 2, WCOLS = BN / 2;
  constexpr int MR = WROWS / 16, NR = WCOLS / 16;
  constexpr int ALOADS = BM / 64, BLOADS = BN / 64;
  constexpr int NLOADS = ALOADS + BLOADS;
  __shared__ __align__(16) ushort Als[DEPTH][BM * 32];
  __shared__ __align__(16) ushort Bls[DEPTH][BN * 32];
  const int tid = threadIdx.x;
  const int lane = tid & 63;
  const int w = tid >> 6;
  const int wr = w >> 1, wc = w & 1;
  const int bid = blockIdx.y * gridDim.x + blockIdx.x;
  const int xcd = bid & 7;
  const int i0 = bid >> 3;
  const int CR = gridDim.x / XR, CC = gridDim.y / XC;
  int rt, ct;
  if constexpr (CTFAST) {
    rt = (xcd % XR) * CR + (i0 / CC);
    ct = (xcd / XR) * CC + (i0 % CC);
  } else {
    rt = (xcd % XR) * CR + (i0 % CR);
    ct = (xcd / XR) * CC + (i0 / CR);
  }
  const int row0 = rt * BM;
  const int col0 = ct * BN;
  const int koff = blockIdx.z * Klen;
  const ushort* Ab = A + (size_t)row0 * K + koff;
  const ushort* Bb = Bw + (size_t)col0 * K + koff;
  const int sr = tid >> 2;  // staging row 0..63
  const int scA = (((tid & 3) ^ ((tid >> 3) & 3)) * 8);  // inverse-swizzled source chunk
  const int fr = lane & 15;
  const int fg = lane >> 4;
  f32x4 zero = {0.f, 0.f, 0.f, 0.f};
  f32x4 acc[MR][NR];
#pragma unroll
  for (int m = 0; m < MR; m++)
#pragma unroll
    for (int n = 0; n < NR; n++) acc[m][n] = zero;

  auto stage = [&](int slot, int kt) {
#pragma unroll
    for (int i2 = 0; i2 < ALOADS; i2++)
      gload_lds16(Ab + (size_t)(sr + 64 * i2) * K + kt + scA, &Als[slot][i2 * 2048 + tid * 8]);
#pragma unroll
    for (int i2 = 0; i2 < BLOADS; i2++)
      gload_lds16(Bb + (size_t)(sr + 64 * i2) * K + kt + scA, &Bls[slot][i2 * 2048 + tid * 8]);
  };
  const int nt = Klen >> 5;
#pragma unroll
  for (int p = 0; p < DEPTH - 1; p++) stage(p, p << 5);
  int cur = 0, sbuf = DEPTH - 1;
  for (int t = 0; t < nt; t++) {
    const int ahead = nt - 1 - t;
    if constexpr (DEPTH == 3) {
      if (ahead >= 1) asm volatile("s_waitcnt vmcnt(%0)" ::"i"(NLOADS) : "memory");
      else            asm volatile("s_waitcnt vmcnt(0)" ::: "memory");
    } else {  // DEPTH == 5
      if (ahead >= 3)      asm volatile("s_waitcnt vmcnt(%0)" ::"i"(3 * NLOADS) : "memory");
      else if (ahead == 2) asm volatile("s_waitcnt vmcnt(%0)" ::"i"(2 * NLOADS) : "memory");
      else if (ahead == 1) asm volatile("s_waitcnt vmcnt(%0)" ::"i"(NLOADS) : "memory");
      else                 asm volatile("s_waitcnt vmcnt(0)" ::: "memory");
    }
    __builtin_amdgcn_s_barrier();
    __builtin_amdgcn_sched_barrier(0);
    if (t + DEPTH - 1 < nt) {
      stage(sbuf, (t + DEPTH - 1) << 5);
      sbuf = (sbuf == DEPTH - 1) ? 0 : sbuf + 1;
    }
    bf16x8 af[MR], bfr[NR];
#pragma unroll
    for (int m = 0; m < MR; m++) {
      int rA = wr * WROWS + m * 16 + fr;
      af[m] = *(const bf16x8*)&Als[cur][rA * 32 + ((fg ^ ((rA >> 1) & 3)) << 3)];
    }
#pragma unroll
    for (int n = 0; n < NR; n++) {
      int rB = wc * WCOLS + n * 16 + fr;
      bfr[n] = *(const bf16x8*)&Bls[cur][rB * 32 + ((fg ^ ((rB >> 1) & 3)) << 3)];
    }
    __builtin_amdgcn_s_setprio(1);
#pragma unroll
    for (int m = 0; m < MR; m++)
#pragma unroll
      for (int n = 0; n < NR; n++)
        acc[m][n] = __builtin_amdgcn_mfma_f32_16x16x32_bf16(af[m], bfr[n], acc[m][n], 0, 0, 0);
    __builtin_amdgcn_s_setprio(0);
    cur = (cur == DEPTH - 1) ? 0 : cur + 1;
  }
  const int orow = row0 + wr * WROWS + fg * 4;
  const int ocol = col0 + wc * WCOLS + fr;
  float* Pz = (float*)Cout + (size_t)blockIdx.z * M * N;
#pragma unroll
  for (int m = 0; m < MR; m++) {
#pragma unroll
    for (int j = 0; j < 4; j++) {
      int r = orow + m * 16 + j;
#pragma unroll
      for (int n = 0; n < NR; n++) {
        int cidx = ocol + n * 16;
        size_t idx = (size_t)r * N + cidx;
        float v = acc[m][n][j];
        if (EPI == 0) {
          ((ushort*)Cout)[idx] = f2bf(v);
        } else if (EPI == 1) {
          ((ushort*)Cout)[idx] = f2bf(((const float*)resid)[idx] + v);
        } else if (EPI == 2) {
          float g = 0.5f * v * (1.0f + tanhf(0.7978845608f * (v + 0.044715f * v * v * v)));
          ((ushort*)Cout)[idx] = f2bf(g);
        } else if (EPI == 3) {
          ((float*)Cout)[idx] = bf2f(((const ushort*)resid)[idx]) + v;
        } else {
          Pz[idx] = v;
        }
      }
    }
  }
}

// ---------------- split-K reduce: out = bf16resid + P0 + P1 (f32x4 lanes) --------------
__global__ __launch_bounds__(256) void reduce_down_kernel(const float* __restrict__ P0,
                                                          const float* __restrict__ P1,
                                                          const ushort* __restrict__ residb,
                                                          float* __restrict__ out) {
  int i = blockIdx.x * 256 + threadIdx.x;  // f32x4 index, 1M total
  float4 a = ((const float4*)P0)[i];
  float4 b = ((const float4*)P1)[i];
  ushort4 r = ((const ushort4*)residb)[i];
  float4 o;
  o.x = a.x + b.x + bf2f(r.x);
  o.y = a.y + b.y + bf2f(r.y);
  o.z = a.z + b.z + bf2f(r.z);
  o.w = a.w + b.w + bf2f(r.w);
  ((float4*)out)[i] = o;
}

// ---------------- RoPE + cosine-sim scaling. One wave per (b,l,h); lane = dh -------------
__global__ __launch_bounds__(256) void rope_kernel(const ushort* __restrict__ qkv,
                                                   const float* __restrict__ pos,
                                                   const float* __restrict__ pos_orig,
                                                   const float* __restrict__ timep,
                                                   const float* __restrict__ qk_scale,
                                                   ushort* __restrict__ qr,
                                                   ushort* __restrict__ kr) {
  int gw = (blockIdx.x * 256 + threadIdx.x) >> 6;  // (b*L + l)*H + h
  int lane = threadIdx.x & 63;
  int h = gw & 15;
  int row = gw >> 4;           // b*L + l
  int b = row >> 11;           // / L_
  int l = row & (L_ - 1);
  float qv = bf2f(qkv[(size_t)row * 3072 + h * 64 + lane]);
  float kv = bf2f(qkv[(size_t)row * 3072 + 1024 + h * 64 + lane]);
  float c = 1.0f, s = 0.0f;
  if (lane < 50) {
    int idx = lane < 25 ? lane : lane - 25;
    int sg = idx / 5, d = idx % 5;
    int fi = d * 16 + h;
    float th;
    if (sg == 4) {
      th = timep[row] * __expf(-(float)fi * 0.05756462732485115f);
    } else {
      float fr = 3.14159265358979323846f * __expf((float)fi * 0.028782313662425575f);
      const float* psrc = (sg == 0 || sg == 2) ? pos_orig : pos;
      int comp = (sg < 2) ? 1 : 0;
      th = (2.0f * psrc[(size_t)row * 2 + comp] - 1.0f) * fr;
    }
    s = sinf(th);
    c = cosf(th);
  }
  int partner = lane < 25 ? lane + 25 : lane - 25;
  float qp = __shfl(qv, partner, 64);
  float kp = __shfl(kv, partner, 64);
  float yq, yk;
  if (lane < 25) { yq = qv * c - qp * s; yk = kv * c - kp * s; }
  else if (lane < 50) { yq = qv * c + qp * s; yk = kv * c + kp * s; }
  else { yq = qv; yk = kv; }
  float sq = yq * yq, sk = yk * yk;
#pragma unroll
  for (int d = 1; d < 64; d <<= 1) { sq += __shfl_xor(sq, d); sk += __shfl_xor(sk, d); }
  float scl = sqrtf(qk_scale[h]);
  float qo = yq * scl * rsqrtf(sq + 1e-6f);
  float ko = yk * scl * rsqrtf(sk + 1e-6f);
  size_t o = ((size_t)(b * 16 + h) * L_ + l) * 64 + lane;
  qr[o] = f2bf(qo);
  kr[o] = f2bf(ko);
}

// ---------------- V transpose: qkv v-slice (b,l,h,dh) -> vT (b,h,dh,l) ----------------
__global__ __launch_bounds__(256) void vtrans_kernel(const ushort* __restrict__ qkv,
                                                     ushort* __restrict__ vT) {
  __shared__ __align__(16) ushort tile[64][72];
  int t = threadIdx.x;
  int lt = blockIdx.x;  // l tile of 64
  int bh = blockIdx.y;
  int b = bh >> 4, h = bh & 15;
  int r = t >> 3, c0 = (t & 7) * 8;
#pragma unroll
  for (int half = 0; half < 2; half++) {
    const ushort* src =
        qkv + (size_t)(b * L_ + lt * 64 + r + half * 32) * 3072 + 2048 + h * 64 + c0;
    *(uint4*)&tile[r + half * 32][c0] = *(const uint4*)src;
  }
  __syncthreads();
#pragma unroll
  for (int half = 0; half < 2; half++) {
    int dh = r + half * 32;
    unsigned p0 = (unsigned)tile[c0 + 0][dh] | ((unsigned)tile[c0 + 1][dh] << 16);
    unsigned p1 = (unsigned)tile[c0 + 2][dh] | ((unsigned)tile[c0 + 3][dh] << 16);
    unsigned p2 = (unsigned)tile[c0 + 4][dh] | ((unsigned)tile[c0 + 5][dh] << 16);
    unsigned p3 = (unsigned)tile[c0 + 6][dh] | ((unsigned)tile[c0 + 7][dh] << 16);
    uint4 o; o.x = p0; o.y = p1; o.z = p2; o.w = p3;
    *(uint4*)&vT[((size_t)bh * 64 + dh) * L_ + lt * 64 + c0] = o;
  }
}

// ---------------- Flash attention, 2x64-row q-sets per block, 4 waves x 16 q-rows ------
// Constant-max softmax via exp2(fma(s, log2e, -12*log2e)) (cosine-sim bound).
// Row-sum via ones-column MFMA: acc1 = mfma(pa, ones, acc1) gives every lane its own
// rows' softmax denominators (no VALU adds, no final shfl reduce).
// Both q-sets share each staged K/V tile -> staging/barrier cost per element halved.
// XCD-locality remap unchanged (each XCD owns 4 heads, 2MB L2-resident K/V).
__global__ __launch_bounds__(256) void attn_kernel(const ushort* __restrict__ qr,
                                                   const ushort* __restrict__ kr,
                                                   const ushort* __restrict__ vT,
                                                   ushort* __restrict__ attnb) {
  __shared__ __align__(16) ushort Kls[2][64 * 64];
  __shared__ __align__(16) ushort Vls[2][64 * 64];
  __shared__ __align__(16) ushort Pls[4][16 * 64];
  const int tid = threadIdx.x, lane = tid & 63, w = tid >> 6;
  const int bid = blockIdx.x;
  const int qp = (bid >> 3) & 15;                 // q-pair index (128 rows)
  const int bh = (bid & 7) | ((bid >> 7) << 3);   // XCD (bid&7) owns heads {x,x+8,x+16,x+24}
  const int b = bh >> 4;
  const int fr = lane & 15, fg = lane >> 4;
  const ushort* Qb0 = qr + ((size_t)bh * L_ + qp * 128 + w * 16) * 64;
  const ushort* Qb1 = Qb0 + 64 * 64;
  bf16x8 qf0[2], qf1[2];
#pragma unroll
  for (int c = 0; c < 2; c++) {
    qf0[c] = *(const bf16x8*)(Qb0 + fr * 64 + c * 32 + fg * 8);
    qf1[c] = *(const bf16x8*)(Qb1 + fr * 64 + c * 32 + fg * 8);
  }
  const ushort ob[8] = {0x3F80, 0x3F80, 0x3F80, 0x3F80, 0x3F80, 0x3F80, 0x3F80, 0x3F80};
  const bf16x8 ones = *(const bf16x8*)ob;
  f32x4 zero = {0.f, 0.f, 0.f, 0.f};
  f32x4 accO0[4], accO1[4], acc1_0 = zero, acc1_1 = zero;
#pragma unroll
  for (int n = 0; n < 4; n++) { accO0[n] = zero; accO1[n] = zero; }
  const int sr = tid >> 3;
  const int scz = (((tid & 7) ^ (sr & 7)) * 8);
  auto stage = [&](int buf, int kt) {
    gload_lds16(kr + ((size_t)bh * L_ + kt + sr) * 64 + scz, &Kls[buf][tid * 8]);
    gload_lds16(kr + ((size_t)bh * L_ + kt + 32 + sr) * 64 + scz, &Kls[buf][2048 + tid * 8]);
    gload_lds16(vT + ((size_t)bh * 64 + sr) * L_ + kt + scz, &Vls[buf][tid * 8]);
    gload_lds16(vT + ((size_t)bh * 64 + 32 + sr) * L_ + kt + scz, &Vls[buf][2048 + tid * 8]);
  };
  stage(0, 0);
  int cur = 0;
  for (int t = 0; t < (L_ >> 6); t++) {
    asm volatile("s_waitcnt vmcnt(0)" ::: "memory");
    __builtin_amdgcn_s_barrier();
    __builtin_amdgcn_sched_barrier(0);
    if (t + 1 < (L_ >> 6)) stage(cur ^ 1, (t + 1) << 6);
#pragma unroll
    for (int qs = 0; qs < 2; qs++) {
      const bf16x8* qf = qs ? qf1 : qf0;
      f32x4* accO = qs ? accO1 : accO0;
      f32x4& acc1 = qs ? acc1_1 : acc1_0;
      f32x4 sv[4];
#pragma unroll
      for (int n = 0; n < 4; n++) sv[n] = zero;
      __builtin_amdgcn_s_setprio(1);
#pragma unroll
      for (int c = 0; c < 2; c++) {
#pragma unroll
        for (int n = 0; n < 4; n++) {
          bf16x8 kf =
              *(const bf16x8*)&Kls[cur][(n * 16 + fr) * 64 + (((c * 4 + fg) ^ (fr & 7)) << 3)];
          sv[n] = __builtin_amdgcn_mfma_f32_16x16x32_bf16(qf[c], kf, sv[n], 0, 0, 0);
        }
      }
      __builtin_amdgcn_s_setprio(0);
      // P = exp(s - 12) = exp2(s*log2e - 12*log2e); truncate to bf16 into Pls
#pragma unroll
      for (int j = 0; j < 4; j++) {
        int row = fg * 4 + j;
        int rbase = row * 64;
        int rx = row & 7;
#pragma unroll
        for (int n = 0; n < 4; n++) {
          float p = __builtin_amdgcn_exp2f(
              fmaf(sv[n][j], 1.4426950408889634f, -17.31234049066756f));
          int chunk = 2 * n + (fr >> 3);
          Pls[w][rbase + ((chunk ^ rx) << 3) + (fr & 7)] =
              (ushort)(__float_as_uint(p) >> 16);
        }
      }
      __builtin_amdgcn_s_setprio(1);
#pragma unroll
      for (int c = 0; c < 2; c++) {
        bf16x8 pa = *(const bf16x8*)&Pls[w][fr * 64 + (((c * 4 + fg) ^ (fr & 7)) << 3)];
#pragma unroll
        for (int n = 0; n < 4; n++) {
          bf16x8 vb =
              *(const bf16x8*)&Vls[cur][(n * 16 + fr) * 64 + (((c * 4 + fg) ^ (fr & 7)) << 3)];
          accO[n] = __builtin_amdgcn_mfma_f32_16x16x32_bf16(pa, vb, accO[n], 0, 0, 0);
        }
        acc1 = __builtin_amdgcn_mfma_f32_16x16x32_bf16(pa, ones, acc1, 0, 0, 0);
      }
      __builtin_amdgcn_s_setprio(0);
    }
    cur ^= 1;
  }
#pragma unroll
  for (int qs = 0; qs < 2; qs++) {
    const f32x4* accO = qs ? accO1 : accO0;
    const f32x4& acc1 = qs ? acc1_1 : acc1_0;
    float inv[4];
#pragma unroll
    for (int j = 0; j < 4; j++) inv[j] = 1.0f / acc1[j];
#pragma unroll
    for (int n = 0; n < 4; n++) {
#pragma unroll
      for (int j = 0; j < 4; j++) {
        float o = accO[n][j] * inv[j];
        int qrow = qp * 128 + qs * 64 + w * 16 + fg * 4 + j;
        int dh = fr + n * 16;
        attnb[(size_t)(b * L_ + qrow) * 1024 + (bh & 15) * 64 + dh] = f2bf(o);
      }
    }
  }
}

extern "C" void kernel_launch(void* const* d_in, const int* in_sizes, int n_in,
                              void* d_out, int out_size, void* d_ws, size_t ws_size,
                              hipStream_t stream) {
  const float* x = (const float*)d_in[0];
  const float* pos = (const float*)d_in[1];
  const float* pos_orig = (const float*)d_in[2];
  const float* timep = (const float*)d_in[3];
  const float* w_qkv = (const float*)d_in[4];
  const float* w_out = (const float*)d_in[5];
  const float* w_up = (const float*)d_in[6];
  const float* w_down = (const float*)d_in[7];
  const float* norm1 = (const float*)d_in[8];
  const float* norm2 = (const float*)d_in[9];
  const float* qk_scale = (const float*)d_in[10];
  float* out = (float*)d_out;
  char* ws = (char*)d_ws;
  size_t off = 0;
  auto alloc = [&](size_t bytes) {
    void* p = ws + off;
    off += bytes;
    return p;
  };
  ushort* xn = (ushort*)alloc(8ull << 20);      // rmsnorm out, reused as h2
  ushort* qkvb = (ushort*)alloc(32ull << 20);   // qkv, reused as gelu-out g (32MB)
  ushort* qrb = (ushort*)alloc(8ull << 20);     // } qrb..attnb (32MB) reused as f32
  ushort* krb = (ushort*)alloc(8ull << 20);     // } split-K partials P0,P1 (16MB each)
  ushort* vTb = (ushort*)alloc(8ull << 20);     // } after attn/out-gemm complete
  ushort* attnb = (ushort*)alloc(8ull << 20);   // }
  ushort* x1b = (ushort*)alloc(8ull << 20);     // bf16 residual x1
  ushort* wqkvb = (ushort*)alloc(6ull << 20);
  ushort* woutb = (ushort*)alloc(2ull << 20);
  ushort* wupb = (ushort*)alloc(8ull << 20);
  ushort* wdownb = (ushort*)alloc(8ull << 20);
  float* Ppart = (float*)qrb;  // P0 = Ppart, P1 = Ppart + 4M floats

  cast_all_kernel<<<12288, 256, 0, stream>>>(w_qkv, w_out, w_up, w_down,
                                             wqkvb, woutb, wupb, wdownb);

  rmsnorm_kernel<float><<<4096, 256, 0, stream>>>(x, norm1, xn);
  // qkv: 128x128 depth3, rt-fastest (A-slice 2MB resident)
  gemm_nt<0, 128, 128, 3, 4, 2, false><<<dim3(32, 24), 256, 0, stream>>>(
      xn, wqkvb, qkvb, nullptr, 4096, 3072, 1024, 1024);
  rope_kernel<<<16384, 256, 0, stream>>>(qkvb, pos, pos_orig, timep, qk_scale, qrb, krb);
  vtrans_kernel<<<dim3(32, 32), 256, 0, stream>>>(qkvb, vTb);
  attn_kernel<<<512, 256, 0, stream>>>(qrb, krb, vTb, attnb);
  // out: 64x64 depth5 grid(64,16) -- R7-proven config (2 blocks/CU)
  gemm_nt<1, 64, 64, 5, 4, 2, false><<<dim3(64, 16), 256, 0, stream>>>(
      attnb, woutb, x1b, x, 4096, 1024, 1024, 1024);
  rmsnorm_kernel<ushort><<<4096, 256, 0, stream>>>(x1b, norm2, xn);
  // up: 128x128 depth3, rt-fastest
  gemm_nt<2, 128, 128, 3, 4, 2, false><<<dim3(32, 32), 256, 0, stream>>>(
      xn, wupb, qkvb, nullptr, 4096, 4096, 1024, 1024);
  // down: split-K=2 in ONE dispatch (grid z=2 -> 512 blocks, 2/CU, depth3=48KB LDS);
  // z writes f32 partial at Ppart + z*4M; ct-fastest XCD map
  gemm_nt<4, 128, 128, 3, 4, 2, true><<<dim3(32, 8, 2), 256, 0, stream>>>(
      qkvb, wdownb, Ppart, nullptr, 4096, 1024, 4096, 2048);
  reduce_down_kernel<<<4096, 256, 0, stream>>>(Ppart, Ppart + (4u << 20), x1b, out);
}

// Round 12
// 284.325 us; speedup vs baseline: 1.0772x; 1.0027x over previous
//
#include <hip/hip_runtime.h>

#define B_ 2
#define L_ 2048
#define D_ 1024
#define H_ 16
#define DH_ 64

typedef float f32x4 __attribute__((ext_vector_type(4)));
typedef __bf16 bf16x8 __attribute__((ext_vector_type(8)));

__device__ __forceinline__ ushort f2bf(float f) {
  unsigned u = __float_as_uint(f);
  u += 0x7fffu + ((u >> 16) & 1u);
  return (ushort)(u >> 16);
}
__device__ __forceinline__ float bf2f(ushort h) {
  return __uint_as_float(((unsigned)h) << 16);
}

__device__ __forceinline__ void gload_lds16(const void* g, void* l) {
  __builtin_amdgcn_global_load_lds(
      (const __attribute__((address_space(1))) unsigned*)g,
      (__attribute__((address_space(3))) unsigned*)l, 16, 0, 0);
}

// ---------------- cast f32 -> bf16, all four weights in one launch ----------------
__global__ __launch_bounds__(256) void cast_all_kernel(const float* __restrict__ w0,
                                                       const float* __restrict__ w1,
                                                       const float* __restrict__ w2,
                                                       const float* __restrict__ w3,
                                                       ushort* __restrict__ o0,
                                                       ushort* __restrict__ o1,
                                                       ushort* __restrict__ o2,
                                                       ushort* __restrict__ o3) {
  int i = blockIdx.x * 256 + threadIdx.x;
  const float* src;
  ushort* dst;
  int j = i;
  if (j < 786432) { src = w0; dst = o0; }
  else if (j < 786432 + 262144) { j -= 786432; src = w1; dst = o1; }
  else if (j < 786432 + 262144 + 1048576) { j -= 786432 + 262144; src = w2; dst = o2; }
  else { j -= 786432 + 262144 + 1048576; src = w3; dst = o3; }
  float4 v = ((const float4*)src)[j];
  ushort4 o;
  o.x = f2bf(v.x); o.y = f2bf(v.y); o.z = f2bf(v.z); o.w = f2bf(v.w);
  ((ushort4*)dst)[j] = o;
}

// ---------------- RMSNorm (T in, bf16 out), one block per row of 1024 ----------------
template <typename T>
__global__ __launch_bounds__(256) void rmsnorm_kernel(const T* __restrict__ x,
                                                      const float* __restrict__ scale,
                                                      ushort* __restrict__ out) {
  int row = blockIdx.x, t = threadIdx.x;
  float4 v;
  if constexpr (sizeof(T) == 4) {
    v = ((const float4*)((const float*)x + (size_t)row * D_))[t];
  } else {
    ushort4 u = ((const ushort4*)((const ushort*)x + (size_t)row * D_))[t];
    v.x = bf2f(u.x); v.y = bf2f(u.y); v.z = bf2f(u.z); v.w = bf2f(u.w);
  }
  float ss = v.x * v.x + v.y * v.y + v.z * v.z + v.w * v.w;
#pragma unroll
  for (int d = 1; d < 64; d <<= 1) ss += __shfl_xor(ss, d);
  __shared__ float wsum[4];
  if ((t & 63) == 0) wsum[t >> 6] = ss;
  __syncthreads();
  float tot = wsum[0] + wsum[1] + wsum[2] + wsum[3];
  float r = rsqrtf(tot * (1.0f / D_) + 1e-6f);
  float4 sc = ((const float4*)scale)[t];
  ushort4 o;
  o.x = f2bf(v.x * sc.x * r); o.y = f2bf(v.y * sc.y * r);
  o.z = f2bf(v.z * sc.z * r); o.w = f2bf(v.w * sc.w * r);
  ((ushort4*)(out + (size_t)row * D_))[t] = o;
}

// ---------------- NT GEMM: C[m][n] = sum_k A[m][k]*Bw[n][k]  (bf16 in, fp32 acc) ---------
// Ring-buffered LDS pipeline (DEPTH in {3,4,5}), raw s_barrier + counted vmcnt ladder:
// steady vmcnt((DEPTH-2)*NLOADS) -> tile t's loads get DEPTH-2 K-steps + cross-block
// interleave to land (L3-hit ~600cyc for producer-written operands). DEPTH=4 is the max
// that keeps 2 blocks/CU at BM=BN=128 (64KB LDS; 2x80KB does NOT fit, R8).
// LDS chunk-XOR swizzle via pre-swizzled gload source (conflict-free).
// split-K via gridDim.z: block z covers [z*Klen,(z+1)*Klen), EPI 4 stores f32 partial
// at Cout + z*M*N. XCD chunking: XR x XC rect; CTFAST picks the L2-hot operand.
// EPI 0: bf16 acc. EPI 1: bf16 (residf32+acc). EPI 2: bf16 gelu(acc).
// EPI 3: f32 (residbf16+acc). EPI 4: f32 raw acc partial at z-offset.
template <int EPI, int BM, int BN, int DEPTH, int XR, int XC, bool CTFAST>
__global__ __launch_bounds__(256) void gemm_nt(const ushort* __restrict__ A,
                                               const ushort* __restrict__ Bw,
                                               void* __restrict__ Cout,
                                               const void* __restrict__ resid,
                                               int M, int N, int K, int Klen) {
  constexpr int WROWS = BM / 2, WCOLS = BN / 2;
  constexpr int MR = WROWS / 16, NR = WCOLS / 16;
  constexpr int ALOADS = BM / 64, BLOADS = BN / 64;
  constexpr int NLOADS = ALOADS + BLOADS;
  __shared__ __align__(16) ushort Als[DEPTH][BM * 32];
  __shared__ __align__(16) ushort Bls[DEPTH][BN * 32];
  const int tid = threadIdx.x;
  const int lane = tid & 63;
  const int w = tid >> 6;
  const int wr = w >> 1, wc = w & 1;
  const int bid = blockIdx.y * gridDim.x + blockIdx.x;
  const int xcd = bid & 7;
  const int i0 = bid >> 3;
  const int CR = gridDim.x / XR, CC = gridDim.y / XC;
  int rt, ct;
  if constexpr (CTFAST) {
    rt = (xcd % XR) * CR + (i0 / CC);
    ct = (xcd / XR) * CC + (i0 % CC);
  } else {
    rt = (xcd % XR) * CR + (i0 % CR);
    ct = (xcd / XR) * CC + (i0 / CR);
  }
  const int row0 = rt * BM;
  const int col0 = ct * BN;
  const int koff = blockIdx.z * Klen;
  const ushort* Ab = A + (size_t)row0 * K + koff;
  const ushort* Bb = Bw + (size_t)col0 * K + koff;
  const int sr = tid >> 2;  // staging row 0..63
  const int scA = (((tid & 3) ^ ((tid >> 3) & 3)) * 8);  // inverse-swizzled source chunk
  const int fr = lane & 15;
  const int fg = lane >> 4;
  f32x4 zero = {0.f, 0.f, 0.f, 0.f};
  f32x4 acc[MR][NR];
#pragma unroll
  for (int m = 0; m < MR; m++)
#pragma unroll
    for (int n = 0; n < NR; n++) acc[m][n] = zero;

  auto stage = [&](int slot, int kt) {
#pragma unroll
    for (int i2 = 0; i2 < ALOADS; i2++)
      gload_lds16(Ab + (size_t)(sr + 64 * i2) * K + kt + scA, &Als[slot][i2 * 2048 + tid * 8]);
#pragma unroll
    for (int i2 = 0; i2 < BLOADS; i2++)
      gload_lds16(Bb + (size_t)(sr + 64 * i2) * K + kt + scA, &Bls[slot][i2 * 2048 + tid * 8]);
  };
  const int nt = Klen >> 5;
#pragma unroll
  for (int p = 0; p < DEPTH - 1; p++) stage(p, p << 5);
  int cur = 0, sbuf = DEPTH - 1;
  for (int t = 0; t < nt; t++) {
    const int ahead = nt - 1 - t;
    if constexpr (DEPTH == 3) {
      if (ahead >= 1) asm volatile("s_waitcnt vmcnt(%0)" ::"i"(NLOADS) : "memory");
      else            asm volatile("s_waitcnt vmcnt(0)" ::: "memory");
    } else if constexpr (DEPTH == 4) {
      if (ahead >= 2)      asm volatile("s_waitcnt vmcnt(%0)" ::"i"(2 * NLOADS) : "memory");
      else if (ahead == 1) asm volatile("s_waitcnt vmcnt(%0)" ::"i"(NLOADS) : "memory");
      else                 asm volatile("s_waitcnt vmcnt(0)" ::: "memory");
    } else {  // DEPTH == 5
      if (ahead >= 3)      asm volatile("s_waitcnt vmcnt(%0)" ::"i"(3 * NLOADS) : "memory");
      else if (ahead == 2) asm volatile("s_waitcnt vmcnt(%0)" ::"i"(2 * NLOADS) : "memory");
      else if (ahead == 1) asm volatile("s_waitcnt vmcnt(%0)" ::"i"(NLOADS) : "memory");
      else                 asm volatile("s_waitcnt vmcnt(0)" ::: "memory");
    }
    __builtin_amdgcn_s_barrier();
    __builtin_amdgcn_sched_barrier(0);
    if (t + DEPTH - 1 < nt) {
      stage(sbuf, (t + DEPTH - 1) << 5);
      sbuf = (sbuf == DEPTH - 1) ? 0 : sbuf + 1;
    }
    bf16x8 af[MR], bfr[NR];
#pragma unroll
    for (int m = 0; m < MR; m++) {
      int rA = wr * WROWS + m * 16 + fr;
      af[m] = *(const bf16x8*)&Als[cur][rA * 32 + ((fg ^ ((rA >> 1) & 3)) << 3)];
    }
#pragma unroll
    for (int n = 0; n < NR; n++) {
      int rB = wc * WCOLS + n * 16 + fr;
      bfr[n] = *(const bf16x8*)&Bls[cur][rB * 32 + ((fg ^ ((rB >> 1) & 3)) << 3)];
    }
    __builtin_amdgcn_s_setprio(1);
#pragma unroll
    for (int m = 0; m < MR; m++)
#pragma unroll
      for (int n = 0; n < NR; n++)
        acc[m][n] = __builtin_amdgcn_mfma_f32_16x16x32_bf16(af[m], bfr[n], acc[m][n], 0, 0, 0);
    __builtin_amdgcn_s_setprio(0);
    cur = (cur == DEPTH - 1) ? 0 : cur + 1;
  }
  const int orow = row0 + wr * WROWS + fg * 4;
  const int ocol = col0 + wc * WCOLS + fr;
  float* Pz = (float*)Cout + (size_t)blockIdx.z * M * N;
#pragma unroll
  for (int m = 0; m < MR; m++) {
#pragma unroll
    for (int j = 0; j < 4; j++) {
      int r = orow + m * 16 + j;
#pragma unroll
      for (int n = 0; n < NR; n++) {
        int cidx = ocol + n * 16;
        size_t idx = (size_t)r * N + cidx;
        float v = acc[m][n][j];
        if (EPI == 0) {
          ((ushort*)Cout)[idx] = f2bf(v);
        } else if (EPI == 1) {
          ((ushort*)Cout)[idx] = f2bf(((const float*)resid)[idx] + v);
        } else if (EPI == 2) {
          float g = 0.5f * v * (1.0f + tanhf(0.7978845608f * (v + 0.044715f * v * v * v)));
          ((ushort*)Cout)[idx] = f2bf(g);
        } else if (EPI == 3) {
          ((float*)Cout)[idx] = bf2f(((const ushort*)resid)[idx]) + v;
        } else {
          Pz[idx] = v;
        }
      }
    }
  }
}

// ---------------- split-K reduce: out = bf16resid + P0 + P1 (f32x4 lanes) --------------
__global__ __launch_bounds__(256) void reduce_down_kernel(const float* __restrict__ P0,
                                                          const float* __restrict__ P1,
                                                          const ushort* __restrict__ residb,
                                                          float* __restrict__ out) {
  int i = blockIdx.x * 256 + threadIdx.x;  // f32x4 index, 1M total
  float4 a = ((const float4*)P0)[i];
  float4 b = ((const float4*)P1)[i];
  ushort4 r = ((const ushort4*)residb)[i];
  float4 o;
  o.x = a.x + b.x + bf2f(r.x);
  o.y = a.y + b.y + bf2f(r.y);
  o.z = a.z + b.z + bf2f(r.z);
  o.w = a.w + b.w + bf2f(r.w);
  ((float4*)out)[i] = o;
}

// ---------------- RoPE + cosine-sim scaling. One wave per (b,l,h); lane = dh -------------
__global__ __launch_bounds__(256) void rope_kernel(const ushort* __restrict__ qkv,
                                                   const float* __restrict__ pos,
                                                   const float* __restrict__ pos_orig,
                                                   const float* __restrict__ timep,
                                                   const float* __restrict__ qk_scale,
                                                   ushort* __restrict__ qr,
                                                   ushort* __restrict__ kr) {
  int gw = (blockIdx.x * 256 + threadIdx.x) >> 6;  // (b*L + l)*H + h
  int lane = threadIdx.x & 63;
  int h = gw & 15;
  int row = gw >> 4;           // b*L + l
  int b = row >> 11;           // / L_
  int l = row & (L_ - 1);
  float qv = bf2f(qkv[(size_t)row * 3072 + h * 64 + lane]);
  float kv = bf2f(qkv[(size_t)row * 3072 + 1024 + h * 64 + lane]);
  float c = 1.0f, s = 0.0f;
  if (lane < 50) {
    int idx = lane < 25 ? lane : lane - 25;
    int sg = idx / 5, d = idx % 5;
    int fi = d * 16 + h;
    float th;
    if (sg == 4) {
      th = timep[row] * __expf(-(float)fi * 0.05756462732485115f);
    } else {
      float fr = 3.14159265358979323846f * __expf((float)fi * 0.028782313662425575f);
      const float* psrc = (sg == 0 || sg == 2) ? pos_orig : pos;
      int comp = (sg < 2) ? 1 : 0;
      th = (2.0f * psrc[(size_t)row * 2 + comp] - 1.0f) * fr;
    }
    s = sinf(th);
    c = cosf(th);
  }
  int partner = lane < 25 ? lane + 25 : lane - 25;
  float qp = __shfl(qv, partner, 64);
  float kp = __shfl(kv, partner, 64);
  float yq, yk;
  if (lane < 25) { yq = qv * c - qp * s; yk = kv * c - kp * s; }
  else if (lane < 50) { yq = qv * c + qp * s; yk = kv * c + kp * s; }
  else { yq = qv; yk = kv; }
  float sq = yq * yq, sk = yk * yk;
#pragma unroll
  for (int d = 1; d < 64; d <<= 1) { sq += __shfl_xor(sq, d); sk += __shfl_xor(sk, d); }
  float scl = sqrtf(qk_scale[h]);
  float qo = yq * scl * rsqrtf(sq + 1e-6f);
  float ko = yk * scl * rsqrtf(sk + 1e-6f);
  size_t o = ((size_t)(b * 16 + h) * L_ + l) * 64 + lane;
  qr[o] = f2bf(qo);
  kr[o] = f2bf(ko);
}

// ---------------- V transpose: qkv v-slice (b,l,h,dh) -> vT (b,h,dh,l) ----------------
__global__ __launch_bounds__(256) void vtrans_kernel(const ushort* __restrict__ qkv,
                                                     ushort* __restrict__ vT) {
  __shared__ __align__(16) ushort tile[64][72];
  int t = threadIdx.x;
  int lt = blockIdx.x;  // l tile of 64
  int bh = blockIdx.y;
  int b = bh >> 4, h = bh & 15;
  int r = t >> 3, c0 = (t & 7) * 8;
#pragma unroll
  for (int half = 0; half < 2; half++) {
    const ushort* src =
        qkv + (size_t)(b * L_ + lt * 64 + r + half * 32) * 3072 + 2048 + h * 64 + c0;
    *(uint4*)&tile[r + half * 32][c0] = *(const uint4*)src;
  }
  __syncthreads();
#pragma unroll
  for (int half = 0; half < 2; half++) {
    int dh = r + half * 32;
    unsigned p0 = (unsigned)tile[c0 + 0][dh] | ((unsigned)tile[c0 + 1][dh] << 16);
    unsigned p1 = (unsigned)tile[c0 + 2][dh] | ((unsigned)tile[c0 + 3][dh] << 16);
    unsigned p2 = (unsigned)tile[c0 + 4][dh] | ((unsigned)tile[c0 + 5][dh] << 16);
    unsigned p3 = (unsigned)tile[c0 + 6][dh] | ((unsigned)tile[c0 + 7][dh] << 16);
    uint4 o; o.x = p0; o.y = p1; o.z = p2; o.w = p3;
    *(uint4*)&vT[((size_t)bh * 64 + dh) * L_ + lt * 64 + c0] = o;
  }
}

// ---------------- Flash attention, 2x64-row q-sets per block, 4 waves x 16 q-rows ------
// Constant-max softmax via exp2(fma(s, log2e, -12*log2e)) (cosine-sim bound).
// Row-sum via ones-column MFMA (every lane gets its own rows' denominators).
// Both q-sets share each staged K/V tile; XCD-locality remap (4 heads/XCD, L2-resident).
__global__ __launch_bounds__(256) void attn_kernel(const ushort* __restrict__ qr,
                                                   const ushort* __restrict__ kr,
                                                   const ushort* __restrict__ vT,
                                                   ushort* __restrict__ attnb) {
  __shared__ __align__(16) ushort Kls[2][64 * 64];
  __shared__ __align__(16) ushort Vls[2][64 * 64];
  __shared__ __align__(16) ushort Pls[4][16 * 64];
  const int tid = threadIdx.x, lane = tid & 63, w = tid >> 6;
  const int bid = blockIdx.x;
  const int qp = (bid >> 3) & 15;                 // q-pair index (128 rows)
  const int bh = (bid & 7) | ((bid >> 7) << 3);   // XCD (bid&7) owns heads {x,x+8,x+16,x+24}
  const int b = bh >> 4;
  const int fr = lane & 15, fg = lane >> 4;
  const ushort* Qb0 = qr + ((size_t)bh * L_ + qp * 128 + w * 16) * 64;
  const ushort* Qb1 = Qb0 + 64 * 64;
  bf16x8 qf0[2], qf1[2];
#pragma unroll
  for (int c = 0; c < 2; c++) {
    qf0[c] = *(const bf16x8*)(Qb0 + fr * 64 + c * 32 + fg * 8);
    qf1[c] = *(const bf16x8*)(Qb1 + fr * 64 + c * 32 + fg * 8);
  }
  const ushort ob[8] = {0x3F80, 0x3F80, 0x3F80, 0x3F80, 0x3F80, 0x3F80, 0x3F80, 0x3F80};
  const bf16x8 ones = *(const bf16x8*)ob;
  f32x4 zero = {0.f, 0.f, 0.f, 0.f};
  f32x4 accO0[4], accO1[4], acc1_0 = zero, acc1_1 = zero;
#pragma unroll
  for (int n = 0; n < 4; n++) { accO0[n] = zero; accO1[n] = zero; }
  const int sr = tid >> 3;
  const int scz = (((tid & 7) ^ (sr & 7)) * 8);
  auto stage = [&](int buf, int kt) {
    gload_lds16(kr + ((size_t)bh * L_ + kt + sr) * 64 + scz, &Kls[buf][tid * 8]);
    gload_lds16(kr + ((size_t)bh * L_ + kt + 32 + sr) * 64 + scz, &Kls[buf][2048 + tid * 8]);
    gload_lds16(vT + ((size_t)bh * 64 + sr) * L_ + kt + scz, &Vls[buf][tid * 8]);
    gload_lds16(vT + ((size_t)bh * 64 + 32 + sr) * L_ + kt + scz, &Vls[buf][2048 + tid * 8]);
  };
  stage(0, 0);
  int cur = 0;
  for (int t = 0; t < (L_ >> 6); t++) {
    asm volatile("s_waitcnt vmcnt(0)" ::: "memory");
    __builtin_amdgcn_s_barrier();
    __builtin_amdgcn_sched_barrier(0);
    if (t + 1 < (L_ >> 6)) stage(cur ^ 1, (t + 1) << 6);
#pragma unroll
    for (int qs = 0; qs < 2; qs++) {
      const bf16x8* qf = qs ? qf1 : qf0;
      f32x4* accO = qs ? accO1 : accO0;
      f32x4& acc1 = qs ? acc1_1 : acc1_0;
      f32x4 sv[4];
#pragma unroll
      for (int n = 0; n < 4; n++) sv[n] = zero;
      __builtin_amdgcn_s_setprio(1);
#pragma unroll
      for (int c = 0; c < 2; c++) {
#pragma unroll
        for (int n = 0; n < 4; n++) {
          bf16x8 kf =
              *(const bf16x8*)&Kls[cur][(n * 16 + fr) * 64 + (((c * 4 + fg) ^ (fr & 7)) << 3)];
          sv[n] = __builtin_amdgcn_mfma_f32_16x16x32_bf16(qf[c], kf, sv[n], 0, 0, 0);
        }
      }
      __builtin_amdgcn_s_setprio(0);
      // P = exp(s - 12) = exp2(s*log2e - 12*log2e); truncate to bf16 into Pls
#pragma unroll
      for (int j = 0; j < 4; j++) {
        int row = fg * 4 + j;
        int rbase = row * 64;
        int rx = row & 7;
#pragma unroll
        for (int n = 0; n < 4; n++) {
          float p = __builtin_amdgcn_exp2f(
              fmaf(sv[n][j], 1.4426950408889634f, -17.31234049066756f));
          int chunk = 2 * n + (fr >> 3);
          Pls[w][rbase + ((chunk ^ rx) << 3) + (fr & 7)] =
              (ushort)(__float_as_uint(p) >> 16);
        }
      }
      __builtin_amdgcn_s_setprio(1);
#pragma unroll
      for (int c = 0; c < 2; c++) {
        bf16x8 pa = *(const bf16x8*)&Pls[w][fr * 64 + (((c * 4 + fg) ^ (fr & 7)) << 3)];
#pragma unroll
        for (int n = 0; n < 4; n++) {
          bf16x8 vb =
              *(const bf16x8*)&Vls[cur][(n * 16 + fr) * 64 + (((c * 4 + fg) ^ (fr & 7)) << 3)];
          accO[n] = __builtin_amdgcn_mfma_f32_16x16x32_bf16(pa, vb, accO[n], 0, 0, 0);
        }
        acc1 = __builtin_amdgcn_mfma_f32_16x16x32_bf16(pa, ones, acc1, 0, 0, 0);
      }
      __builtin_amdgcn_s_setprio(0);
    }
    cur ^= 1;
  }
#pragma unroll
  for (int qs = 0; qs < 2; qs++) {
    const f32x4* accO = qs ? accO1 : accO0;
    const f32x4& acc1 = qs ? acc1_1 : acc1_0;
    float inv[4];
#pragma unroll
    for (int j = 0; j < 4; j++) inv[j] = 1.0f / acc1[j];
#pragma unroll
    for (int n = 0; n < 4; n++) {
#pragma unroll
      for (int j = 0; j < 4; j++) {
        float o = accO[n][j] * inv[j];
        int qrow = qp * 128 + qs * 64 + w * 16 + fg * 4 + j;
        int dh = fr + n * 16;
        attnb[(size_t)(b * L_ + qrow) * 1024 + (bh & 15) * 64 + dh] = f2bf(o);
      }
    }
  }
}

extern "C" void kernel_launch(void* const* d_in, const int* in_sizes, int n_in,
                              void* d_out, int out_size, void* d_ws, size_t ws_size,
                              hipStream_t stream) {
  const float* x = (const float*)d_in[0];
  const float* pos = (const float*)d_in[1];
  const float* pos_orig = (const float*)d_in[2];
  const float* timep = (const float*)d_in[3];
  const float* w_qkv = (const float*)d_in[4];
  const float* w_out = (const float*)d_in[5];
  const float* w_up = (const float*)d_in[6];
  const float* w_down = (const float*)d_in[7];
  const float* norm1 = (const float*)d_in[8];
  const float* norm2 = (const float*)d_in[9];
  const float* qk_scale = (const float*)d_in[10];
  float* out = (float*)d_out;
  char* ws = (char*)d_ws;
  size_t off = 0;
  auto alloc = [&](size_t bytes) {
    void* p = ws + off;
    off += bytes;
    return p;
  };
  ushort* xn = (ushort*)alloc(8ull << 20);      // rmsnorm out, reused as h2
  ushort* qkvb = (ushort*)alloc(32ull << 20);   // qkv, reused as gelu-out g (32MB)
  ushort* qrb = (ushort*)alloc(8ull << 20);     // } qrb..attnb (32MB) reused as f32
  ushort* krb = (ushort*)alloc(8ull << 20);     // } split-K partials P0,P1 (16MB each)
  ushort* vTb = (ushort*)alloc(8ull << 20);     // } after attn/out-gemm complete
  ushort* attnb = (ushort*)alloc(8ull << 20);   // }
  ushort* x1b = (ushort*)alloc(8ull << 20);     // bf16 residual x1
  ushort* wqkvb = (ushort*)alloc(6ull << 20);
  ushort* woutb = (ushort*)alloc(2ull << 20);
  ushort* wupb = (ushort*)alloc(8ull << 20);
  ushort* wdownb = (ushort*)alloc(8ull << 20);
  float* Ppart = (float*)qrb;  // P0 = Ppart, P1 = Ppart + 4M floats

  cast_all_kernel<<<12288, 256, 0, stream>>>(w_qkv, w_out, w_up, w_down,
                                             wqkvb, woutb, wupb, wdownb);

  rmsnorm_kernel<float><<<4096, 256, 0, stream>>>(x, norm1, xn);
  // qkv: 128x128 depth3, rt-fastest (A-slice 2MB resident)
  gemm_nt<0, 128, 128, 3, 4, 2, false><<<dim3(32, 24), 256, 0, stream>>>(
      xn, wqkvb, qkvb, nullptr, 4096, 3072, 1024, 1024);
  rope_kernel<<<16384, 256, 0, stream>>>(qkvb, pos, pos_orig, timep, qk_scale, qrb, krb);
  vtrans_kernel<<<dim3(32, 32), 256, 0, stream>>>(qkvb, vTb);
  attn_kernel<<<512, 256, 0, stream>>>(qrb, krb, vTb, attnb);
  // out: 64x64 depth5 grid(64,16) (2 blocks/CU)
  gemm_nt<1, 64, 64, 5, 4, 2, false><<<dim3(64, 16), 256, 0, stream>>>(
      attnb, woutb, x1b, x, 4096, 1024, 1024, 1024);
  rmsnorm_kernel<ushort><<<4096, 256, 0, stream>>>(x1b, norm2, xn);
  // up: 128x128 depth3, rt-fastest
  gemm_nt<2, 128, 128, 3, 4, 2, false><<<dim3(32, 32), 256, 0, stream>>>(
      xn, wupb, qkvb, nullptr, 4096, 4096, 1024, 1024);
  // down: split-K=2, 128x128 DEPTH=4 (64KB LDS -> 2 blocks/CU, 2-step prefetch cover);
  // z writes f32 partial at Ppart + z*4M; ct-fastest XCD map
  gemm_nt<4, 128, 128, 4, 4, 2, true><<<dim3(32, 8, 2), 256, 0, stream>>>(
      qkvb, wdownb, Ppart, nullptr, 4096, 1024, 4096, 2048);
  reduce_down_kernel<<<4096, 256, 0, stream>>>(Ppart, Ppart + (4u << 20), x1b, out);
}

// Round 13
// 283.089 us; speedup vs baseline: 1.0819x; 1.0044x over previous
//
#include <hip/hip_runtime.h>

#define B_ 2
#define L_ 2048
#define D_ 1024
#define H_ 16
#define DH_ 64

typedef float f32x4 __attribute__((ext_vector_type(4)));
typedef __bf16 bf16x8 __attribute__((ext_vector_type(8)));

__device__ __forceinline__ ushort f2bf(float f) {
  unsigned u = __float_as_uint(f);
  u += 0x7fffu + ((u >> 16) & 1u);
  return (ushort)(u >> 16);
}
__device__ __forceinline__ float bf2f(ushort h) {
  return __uint_as_float(((unsigned)h) << 16);
}

__device__ __forceinline__ void gload_lds16(const void* g, void* l) {
  __builtin_amdgcn_global_load_lds(
      (const __attribute__((address_space(1))) unsigned*)g,
      (__attribute__((address_space(3))) unsigned*)l, 16, 0, 0);
}

// ---------------- cast f32 -> bf16, all four weights in one launch ----------------
__global__ __launch_bounds__(256) void cast_all_kernel(const float* __restrict__ w0,
                                                       const float* __restrict__ w1,
                                                       const float* __restrict__ w2,
                                                       const float* __restrict__ w3,
                                                       ushort* __restrict__ o0,
                                                       ushort* __restrict__ o1,
                                                       ushort* __restrict__ o2,
                                                       ushort* __restrict__ o3) {
  int i = blockIdx.x * 256 + threadIdx.x;
  const float* src;
  ushort* dst;
  int j = i;
  if (j < 786432) { src = w0; dst = o0; }
  else if (j < 786432 + 262144) { j -= 786432; src = w1; dst = o1; }
  else if (j < 786432 + 262144 + 1048576) { j -= 786432 + 262144; src = w2; dst = o2; }
  else { j -= 786432 + 262144 + 1048576; src = w3; dst = o3; }
  float4 v = ((const float4*)src)[j];
  ushort4 o;
  o.x = f2bf(v.x); o.y = f2bf(v.y); o.z = f2bf(v.z); o.w = f2bf(v.w);
  ((ushort4*)dst)[j] = o;
}

// ---------------- RMSNorm (T in, bf16 out), one block per row of 1024 ----------------
template <typename T>
__global__ __launch_bounds__(256) void rmsnorm_kernel(const T* __restrict__ x,
                                                      const float* __restrict__ scale,
                                                      ushort* __restrict__ out) {
  int row = blockIdx.x, t = threadIdx.x;
  float4 v;
  if constexpr (sizeof(T) == 4) {
    v = ((const float4*)((const float*)x + (size_t)row * D_))[t];
  } else {
    ushort4 u = ((const ushort4*)((const ushort*)x + (size_t)row * D_))[t];
    v.x = bf2f(u.x); v.y = bf2f(u.y); v.z = bf2f(u.z); v.w = bf2f(u.w);
  }
  float ss = v.x * v.x + v.y * v.y + v.z * v.z + v.w * v.w;
#pragma unroll
  for (int d = 1; d < 64; d <<= 1) ss += __shfl_xor(ss, d);
  __shared__ float wsum[4];
  if ((t & 63) == 0) wsum[t >> 6] = ss;
  __syncthreads();
  float tot = wsum[0] + wsum[1] + wsum[2] + wsum[3];
  float r = rsqrtf(tot * (1.0f / D_) + 1e-6f);
  float4 sc = ((const float4*)scale)[t];
  ushort4 o;
  o.x = f2bf(v.x * sc.x * r); o.y = f2bf(v.y * sc.y * r);
  o.z = f2bf(v.z * sc.z * r); o.w = f2bf(v.w * sc.w * r);
  ((ushort4*)(out + (size_t)row * D_))[t] = o;
}

// ---------------- NT GEMM: C[m][n] = sum_k A[m][k]*Bw[n][k]  (bf16 in, fp32 acc) ---------
// Ring-buffered LDS pipeline, raw s_barrier + counted vmcnt ladder, NO order pinning:
// sched_barrier(0) removed (m141: pinning caps the structure at ~510 TF; unpinned m97
// schedule reaches ~900) and setprio removed (m190: null-to-negative on lockstep GEMM).
// LDS chunk-XOR swizzle via pre-swizzled gload source (conflict-free).
// split-K via gridDim.z: block z covers [z*Klen,(z+1)*Klen), EPI 4 stores f32 partial
// at Cout + z*M*N. XCD chunking: XR x XC rect; CTFAST picks the L2-hot operand.
// EPI 0: bf16 acc. EPI 1: bf16 (residf32+acc). EPI 2: bf16 gelu(acc).
// EPI 3: f32 (residbf16+acc). EPI 4: f32 raw acc partial at z-offset.
template <int EPI, int BM, int BN, int DEPTH, int XR, int XC, bool CTFAST>
__global__ __launch_bounds__(256) void gemm_nt(const ushort* __restrict__ A,
                                               const ushort* __restrict__ Bw,
                                               void* __restrict__ Cout,
                                               const void* __restrict__ resid,
                                               int M, int N, int K, int Klen) {
  constexpr int WROWS = BM / 2, WCOLS = BN / 2;
  constexpr int MR = WROWS / 16, NR = WCOLS / 16;
  constexpr int ALOADS = BM / 64, BLOADS = BN / 64;
  constexpr int NLOADS = ALOADS + BLOADS;
  __shared__ __align__(16) ushort Als[DEPTH][BM * 32];
  __shared__ __align__(16) ushort Bls[DEPTH][BN * 32];
  const int tid = threadIdx.x;
  const int lane = tid & 63;
  const int w = tid >> 6;
  const int wr = w >> 1, wc = w & 1;
  const int bid = blockIdx.y * gridDim.x + blockIdx.x;
  const int xcd = bid & 7;
  const int i0 = bid >> 3;
  const int CR = gridDim.x / XR, CC = gridDim.y / XC;
  int rt, ct;
  if constexpr (CTFAST) {
    rt = (xcd % XR) * CR + (i0 / CC);
    ct = (xcd / XR) * CC + (i0 % CC);
  } else {
    rt = (xcd % XR) * CR + (i0 % CR);
    ct = (xcd / XR) * CC + (i0 / CR);
  }
  const int row0 = rt * BM;
  const int col0 = ct * BN;
  const int koff = blockIdx.z * Klen;
  const ushort* Ab = A + (size_t)row0 * K + koff;
  const ushort* Bb = Bw + (size_t)col0 * K + koff;
  const int sr = tid >> 2;  // staging row 0..63
  const int scA = (((tid & 3) ^ ((tid >> 3) & 3)) * 8);  // inverse-swizzled source chunk
  const int fr = lane & 15;
  const int fg = lane >> 4;
  f32x4 zero = {0.f, 0.f, 0.f, 0.f};
  f32x4 acc[MR][NR];
#pragma unroll
  for (int m = 0; m < MR; m++)
#pragma unroll
    for (int n = 0; n < NR; n++) acc[m][n] = zero;

  auto stage = [&](int slot, int kt) {
#pragma unroll
    for (int i2 = 0; i2 < ALOADS; i2++)
      gload_lds16(Ab + (size_t)(sr + 64 * i2) * K + kt + scA, &Als[slot][i2 * 2048 + tid * 8]);
#pragma unroll
    for (int i2 = 0; i2 < BLOADS; i2++)
      gload_lds16(Bb + (size_t)(sr + 64 * i2) * K + kt + scA, &Bls[slot][i2 * 2048 + tid * 8]);
  };
  const int nt = Klen >> 5;
#pragma unroll
  for (int p = 0; p < DEPTH - 1; p++) stage(p, p << 5);
  int cur = 0, sbuf = DEPTH - 1;
  for (int t = 0; t < nt; t++) {
    const int ahead = nt - 1 - t;
    if constexpr (DEPTH == 3) {
      if (ahead >= 1) asm volatile("s_waitcnt vmcnt(%0)" ::"i"(NLOADS) : "memory");
      else            asm volatile("s_waitcnt vmcnt(0)" ::: "memory");
    } else if constexpr (DEPTH == 4) {
      if (ahead >= 2)      asm volatile("s_waitcnt vmcnt(%0)" ::"i"(2 * NLOADS) : "memory");
      else if (ahead == 1) asm volatile("s_waitcnt vmcnt(%0)" ::"i"(NLOADS) : "memory");
      else                 asm volatile("s_waitcnt vmcnt(0)" ::: "memory");
    } else {  // DEPTH == 5
      if (ahead >= 3)      asm volatile("s_waitcnt vmcnt(%0)" ::"i"(3 * NLOADS) : "memory");
      else if (ahead == 2) asm volatile("s_waitcnt vmcnt(%0)" ::"i"(2 * NLOADS) : "memory");
      else if (ahead == 1) asm volatile("s_waitcnt vmcnt(%0)" ::"i"(NLOADS) : "memory");
      else                 asm volatile("s_waitcnt vmcnt(0)" ::: "memory");
    }
    __builtin_amdgcn_s_barrier();
    if (t + DEPTH - 1 < nt) {
      stage(sbuf, (t + DEPTH - 1) << 5);
      sbuf = (sbuf == DEPTH - 1) ? 0 : sbuf + 1;
    }
    bf16x8 af[MR], bfr[NR];
#pragma unroll
    for (int m = 0; m < MR; m++) {
      int rA = wr * WROWS + m * 16 + fr;
      af[m] = *(const bf16x8*)&Als[cur][rA * 32 + ((fg ^ ((rA >> 1) & 3)) << 3)];
    }
#pragma unroll
    for (int n = 0; n < NR; n++) {
      int rB = wc * WCOLS + n * 16 + fr;
      bfr[n] = *(const bf16x8*)&Bls[cur][rB * 32 + ((fg ^ ((rB >> 1) & 3)) << 3)];
    }
#pragma unroll
    for (int m = 0; m < MR; m++)
#pragma unroll
      for (int n = 0; n < NR; n++)
        acc[m][n] = __builtin_amdgcn_mfma_f32_16x16x32_bf16(af[m], bfr[n], acc[m][n], 0, 0, 0);
    cur = (cur == DEPTH - 1) ? 0 : cur + 1;
  }
  const int orow = row0 + wr * WROWS + fg * 4;
  const int ocol = col0 + wc * WCOLS + fr;
  float* Pz = (float*)Cout + (size_t)blockIdx.z * M * N;
#pragma unroll
  for (int m = 0; m < MR; m++) {
#pragma unroll
    for (int j = 0; j < 4; j++) {
      int r = orow + m * 16 + j;
#pragma unroll
      for (int n = 0; n < NR; n++) {
        int cidx = ocol + n * 16;
        size_t idx = (size_t)r * N + cidx;
        float v = acc[m][n][j];
        if (EPI == 0) {
          ((ushort*)Cout)[idx] = f2bf(v);
        } else if (EPI == 1) {
          ((ushort*)Cout)[idx] = f2bf(((const float*)resid)[idx] + v);
        } else if (EPI == 2) {
          float g = 0.5f * v * (1.0f + tanhf(0.7978845608f * (v + 0.044715f * v * v * v)));
          ((ushort*)Cout)[idx] = f2bf(g);
        } else if (EPI == 3) {
          ((float*)Cout)[idx] = bf2f(((const ushort*)resid)[idx]) + v;
        } else {
          Pz[idx] = v;
        }
      }
    }
  }
}

// ---------------- split-K reduce: out = bf16resid + P0 + P1 (f32x4 lanes) --------------
__global__ __launch_bounds__(256) void reduce_down_kernel(const float* __restrict__ P0,
                                                          const float* __restrict__ P1,
                                                          const ushort* __restrict__ residb,
                                                          float* __restrict__ out) {
  int i = blockIdx.x * 256 + threadIdx.x;  // f32x4 index, 1M total
  float4 a = ((const float4*)P0)[i];
  float4 b = ((const float4*)P1)[i];
  ushort4 r = ((const ushort4*)residb)[i];
  float4 o;
  o.x = a.x + b.x + bf2f(r.x);
  o.y = a.y + b.y + bf2f(r.y);
  o.z = a.z + b.z + bf2f(r.z);
  o.w = a.w + b.w + bf2f(r.w);
  ((float4*)out)[i] = o;
}

// ---------------- RoPE + cosine-sim scaling. One wave per (b,l,h); lane = dh -------------
__global__ __launch_bounds__(256) void rope_kernel(const ushort* __restrict__ qkv,
                                                   const float* __restrict__ pos,
                                                   const float* __restrict__ pos_orig,
                                                   const float* __restrict__ timep,
                                                   const float* __restrict__ qk_scale,
                                                   ushort* __restrict__ qr,
                                                   ushort* __restrict__ kr) {
  int gw = (blockIdx.x * 256 + threadIdx.x) >> 6;  // (b*L + l)*H + h
  int lane = threadIdx.x & 63;
  int h = gw & 15;
  int row = gw >> 4;           // b*L + l
  int b = row >> 11;           // / L_
  int l = row & (L_ - 1);
  float qv = bf2f(qkv[(size_t)row * 3072 + h * 64 + lane]);
  float kv = bf2f(qkv[(size_t)row * 3072 + 1024 + h * 64 + lane]);
  float c = 1.0f, s = 0.0f;
  if (lane < 50) {
    int idx = lane < 25 ? lane : lane - 25;
    int sg = idx / 5, d = idx % 5;
    int fi = d * 16 + h;
    float th;
    if (sg == 4) {
      th = timep[row] * __expf(-(float)fi * 0.05756462732485115f);
    } else {
      float fr = 3.14159265358979323846f * __expf((float)fi * 0.028782313662425575f);
      const float* psrc = (sg == 0 || sg == 2) ? pos_orig : pos;
      int comp = (sg < 2) ? 1 : 0;
      th = (2.0f * psrc[(size_t)row * 2 + comp] - 1.0f) * fr;
    }
    s = sinf(th);
    c = cosf(th);
  }
  int partner = lane < 25 ? lane + 25 : lane - 25;
  float qp = __shfl(qv, partner, 64);
  float kp = __shfl(kv, partner, 64);
  float yq, yk;
  if (lane < 25) { yq = qv * c - qp * s; yk = kv * c - kp * s; }
  else if (lane < 50) { yq = qv * c + qp * s; yk = kv * c + kp * s; }
  else { yq = qv; yk = kv; }
  float sq = yq * yq, sk = yk * yk;
#pragma unroll
  for (int d = 1; d < 64; d <<= 1) { sq += __shfl_xor(sq, d); sk += __shfl_xor(sk, d); }
  float scl = sqrtf(qk_scale[h]);
  float qo = yq * scl * rsqrtf(sq + 1e-6f);
  float ko = yk * scl * rsqrtf(sk + 1e-6f);
  size_t o = ((size_t)(b * 16 + h) * L_ + l) * 64 + lane;
  qr[o] = f2bf(qo);
  kr[o] = f2bf(ko);
}

// ---------------- V transpose: qkv v-slice (b,l,h,dh) -> vT (b,h,dh,l) ----------------
__global__ __launch_bounds__(256) void vtrans_kernel(const ushort* __restrict__ qkv,
                                                     ushort* __restrict__ vT) {
  __shared__ __align__(16) ushort tile[64][72];
  int t = threadIdx.x;
  int lt = blockIdx.x;  // l tile of 64
  int bh = blockIdx.y;
  int b = bh >> 4, h = bh & 15;
  int r = t >> 3, c0 = (t & 7) * 8;
#pragma unroll
  for (int half = 0; half < 2; half++) {
    const ushort* src =
        qkv + (size_t)(b * L_ + lt * 64 + r + half * 32) * 3072 + 2048 + h * 64 + c0;
    *(uint4*)&tile[r + half * 32][c0] = *(const uint4*)src;
  }
  __syncthreads();
#pragma unroll
  for (int half = 0; half < 2; half++) {
    int dh = r + half * 32;
    unsigned p0 = (unsigned)tile[c0 + 0][dh] | ((unsigned)tile[c0 + 1][dh] << 16);
    unsigned p1 = (unsigned)tile[c0 + 2][dh] | ((unsigned)tile[c0 + 3][dh] << 16);
    unsigned p2 = (unsigned)tile[c0 + 4][dh] | ((unsigned)tile[c0 + 5][dh] << 16);
    unsigned p3 = (unsigned)tile[c0 + 6][dh] | ((unsigned)tile[c0 + 7][dh] << 16);
    uint4 o; o.x = p0; o.y = p1; o.z = p2; o.w = p3;
    *(uint4*)&vT[((size_t)bh * 64 + dh) * L_ + lt * 64 + c0] = o;
  }
}

// ---------------- Flash attention, 2x64-row q-sets per block, 4 waves x 16 q-rows ------
// Constant-max softmax via exp2(fma(s, log2e, -12*log2e)) (cosine-sim bound).
// Row-sum via ones-column MFMA (every lane gets its own rows' denominators).
// Both q-sets share each staged K/V tile; XCD-locality remap (4 heads/XCD, L2-resident).
// setprio kept here (m191: positive on attn-style schedules, unlike GEMM).
__global__ __launch_bounds__(256) void attn_kernel(const ushort* __restrict__ qr,
                                                   const ushort* __restrict__ kr,
                                                   const ushort* __restrict__ vT,
                                                   ushort* __restrict__ attnb) {
  __shared__ __align__(16) ushort Kls[2][64 * 64];
  __shared__ __align__(16) ushort Vls[2][64 * 64];
  __shared__ __align__(16) ushort Pls[4][16 * 64];
  const int tid = threadIdx.x, lane = tid & 63, w = tid >> 6;
  const int bid = blockIdx.x;
  const int qp = (bid >> 3) & 15;                 // q-pair index (128 rows)
  const int bh = (bid & 7) | ((bid >> 7) << 3);   // XCD (bid&7) owns heads {x,x+8,x+16,x+24}
  const int b = bh >> 4;
  const int fr = lane & 15, fg = lane >> 4;
  const ushort* Qb0 = qr + ((size_t)bh * L_ + qp * 128 + w * 16) * 64;
  const ushort* Qb1 = Qb0 + 64 * 64;
  bf16x8 qf0[2], qf1[2];
#pragma unroll
  for (int c = 0; c < 2; c++) {
    qf0[c] = *(const bf16x8*)(Qb0 + fr * 64 + c * 32 + fg * 8);
    qf1[c] = *(const bf16x8*)(Qb1 + fr * 64 + c * 32 + fg * 8);
  }
  const ushort ob[8] = {0x3F80, 0x3F80, 0x3F80, 0x3F80, 0x3F80, 0x3F80, 0x3F80, 0x3F80};
  const bf16x8 ones = *(const bf16x8*)ob;
  f32x4 zero = {0.f, 0.f, 0.f, 0.f};
  f32x4 accO0[4], accO1[4], acc1_0 = zero, acc1_1 = zero;
#pragma unroll
  for (int n = 0; n < 4; n++) { accO0[n] = zero; accO1[n] = zero; }
  const int sr = tid >> 3;
  const int scz = (((tid & 7) ^ (sr & 7)) * 8);
  auto stage = [&](int buf, int kt) {
    gload_lds16(kr + ((size_t)bh * L_ + kt + sr) * 64 + scz, &Kls[buf][tid * 8]);
    gload_lds16(kr + ((size_t)bh * L_ + kt + 32 + sr) * 64 + scz, &Kls[buf][2048 + tid * 8]);
    gload_lds16(vT + ((size_t)bh * 64 + sr) * L_ + kt + scz, &Vls[buf][tid * 8]);
    gload_lds16(vT + ((size_t)bh * 64 + 32 + sr) * L_ + kt + scz, &Vls[buf][2048 + tid * 8]);
  };
  stage(0, 0);
  int cur = 0;
  for (int t = 0; t < (L_ >> 6); t++) {
    asm volatile("s_waitcnt vmcnt(0)" ::: "memory");
    __builtin_amdgcn_s_barrier();
    __builtin_amdgcn_sched_barrier(0);
    if (t + 1 < (L_ >> 6)) stage(cur ^ 1, (t + 1) << 6);
#pragma unroll
    for (int qs = 0; qs < 2; qs++) {
      const bf16x8* qf = qs ? qf1 : qf0;
      f32x4* accO = qs ? accO1 : accO0;
      f32x4& acc1 = qs ? acc1_1 : acc1_0;
      f32x4 sv[4];
#pragma unroll
      for (int n = 0; n < 4; n++) sv[n] = zero;
      __builtin_amdgcn_s_setprio(1);
#pragma unroll
      for (int c = 0; c < 2; c++) {
#pragma unroll
        for (int n = 0; n < 4; n++) {
          bf16x8 kf =
              *(const bf16x8*)&Kls[cur][(n * 16 + fr) * 64 + (((c * 4 + fg) ^ (fr & 7)) << 3)];
          sv[n] = __builtin_amdgcn_mfma_f32_16x16x32_bf16(qf[c], kf, sv[n], 0, 0, 0);
        }
      }
      __builtin_amdgcn_s_setprio(0);
      // P = exp(s - 12) = exp2(s*log2e - 12*log2e); truncate to bf16 into Pls
#pragma unroll
      for (int j = 0; j < 4; j++) {
        int row = fg * 4 + j;
        int rbase = row * 64;
        int rx = row & 7;
#pragma unroll
        for (int n = 0; n < 4; n++) {
          float p = __builtin_amdgcn_exp2f(
              fmaf(sv[n][j], 1.4426950408889634f, -17.31234049066756f));
          int chunk = 2 * n + (fr >> 3);
          Pls[w][rbase + ((chunk ^ rx) << 3) + (fr & 7)] =
              (ushort)(__float_as_uint(p) >> 16);
        }
      }
      __builtin_amdgcn_s_setprio(1);
#pragma unroll
      for (int c = 0; c < 2; c++) {
        bf16x8 pa = *(const bf16x8*)&Pls[w][fr * 64 + (((c * 4 + fg) ^ (fr & 7)) << 3)];
#pragma unroll
        for (int n = 0; n < 4; n++) {
          bf16x8 vb =
              *(const bf16x8*)&Vls[cur][(n * 16 + fr) * 64 + (((c * 4 + fg) ^ (fr & 7)) << 3)];
          accO[n] = __builtin_amdgcn_mfma_f32_16x16x32_bf16(pa, vb, accO[n], 0, 0, 0);
        }
        acc1 = __builtin_amdgcn_mfma_f32_16x16x32_bf16(pa, ones, acc1, 0, 0, 0);
      }
      __builtin_amdgcn_s_setprio(0);
    }
    cur ^= 1;
  }
#pragma unroll
  for (int qs = 0; qs < 2; qs++) {
    const f32x4* accO = qs ? accO1 : accO0;
    const f32x4& acc1 = qs ? acc1_1 : acc1_0;
    float inv[4];
#pragma unroll
    for (int j = 0; j < 4; j++) inv[j] = 1.0f / acc1[j];
#pragma unroll
    for (int n = 0; n < 4; n++) {
#pragma unroll
      for (int j = 0; j < 4; j++) {
        float o = accO[n][j] * inv[j];
        int qrow = qp * 128 + qs * 64 + w * 16 + fg * 4 + j;
        int dh = fr + n * 16;
        attnb[(size_t)(b * L_ + qrow) * 1024 + (bh & 15) * 64 + dh] = f2bf(o);
      }
    }
  }
}

extern "C" void kernel_launch(void* const* d_in, const int* in_sizes, int n_in,
                              void* d_out, int out_size, void* d_ws, size_t ws_size,
                              hipStream_t stream) {
  const float* x = (const float*)d_in[0];
  const float* pos = (const float*)d_in[1];
  const float* pos_orig = (const float*)d_in[2];
  const float* timep = (const float*)d_in[3];
  const float* w_qkv = (const float*)d_in[4];
  const float* w_out = (const float*)d_in[5];
  const float* w_up = (const float*)d_in[6];
  const float* w_down = (const float*)d_in[7];
  const float* norm1 = (const float*)d_in[8];
  const float* norm2 = (const float*)d_in[9];
  const float* qk_scale = (const float*)d_in[10];
  float* out = (float*)d_out;
  char* ws = (char*)d_ws;
  size_t off = 0;
  auto alloc = [&](size_t bytes) {
    void* p = ws + off;
    off += bytes;
    return p;
  };
  ushort* xn = (ushort*)alloc(8ull << 20);      // rmsnorm out, reused as h2
  ushort* qkvb = (ushort*)alloc(32ull << 20);   // qkv, reused as gelu-out g (32MB)
  ushort* qrb = (ushort*)alloc(8ull << 20);     // } qrb..attnb (32MB) reused as f32
  ushort* krb = (ushort*)alloc(8ull << 20);     // } split-K partials P0,P1 (16MB each)
  ushort* vTb = (ushort*)alloc(8ull << 20);     // } after attn/out-gemm complete
  ushort* attnb = (ushort*)alloc(8ull << 20);   // }
  ushort* x1b = (ushort*)alloc(8ull << 20);     // bf16 residual x1
  ushort* wqkvb = (ushort*)alloc(6ull << 20);
  ushort* woutb = (ushort*)alloc(2ull << 20);
  ushort* wupb = (ushort*)alloc(8ull << 20);
  ushort* wdownb = (ushort*)alloc(8ull << 20);
  float* Ppart = (float*)qrb;  // P0 = Ppart, P1 = Ppart + 4M floats

  cast_all_kernel<<<12288, 256, 0, stream>>>(w_qkv, w_out, w_up, w_down,
                                             wqkvb, woutb, wupb, wdownb);

  rmsnorm_kernel<float><<<4096, 256, 0, stream>>>(x, norm1, xn);
  // qkv: 128x128 depth3, rt-fastest (A-slice 2MB resident)
  gemm_nt<0, 128, 128, 3, 4, 2, false><<<dim3(32, 24), 256, 0, stream>>>(
      xn, wqkvb, qkvb, nullptr, 4096, 3072, 1024, 1024);
  rope_kernel<<<16384, 256, 0, stream>>>(qkvb, pos, pos_orig, timep, qk_scale, qrb, krb);
  vtrans_kernel<<<dim3(32, 32), 256, 0, stream>>>(qkvb, vTb);
  attn_kernel<<<512, 256, 0, stream>>>(qrb, krb, vTb, attnb);
  // out: 64x64 depth5 grid(64,16) (2 blocks/CU)
  gemm_nt<1, 64, 64, 5, 4, 2, false><<<dim3(64, 16), 256, 0, stream>>>(
      attnb, woutb, x1b, x, 4096, 1024, 1024, 1024);
  rmsnorm_kernel<ushort><<<4096, 256, 0, stream>>>(x1b, norm2, xn);
  // up: 128x128 depth3, rt-fastest
  gemm_nt<2, 128, 128, 3, 4, 2, false><<<dim3(32, 32), 256, 0, stream>>>(
      xn, wupb, qkvb, nullptr, 4096, 4096, 1024, 1024);
  // down: split-K=2, 128x128 DEPTH=4 (64KB LDS -> 2 blocks/CU);
  // z writes f32 partial at Ppart + z*4M; ct-fastest XCD map
  gemm_nt<4, 128, 128, 4, 4, 2, true><<<dim3(32, 8, 2), 256, 0, stream>>>(
      qkvb, wdownb, Ppart, nullptr, 4096, 1024, 4096, 2048);
  reduce_down_kernel<<<4096, 256, 0, stream>>>(Ppart, Ppart + (4u << 20), x1b, out);
}

// Round 14
// 270.198 us; speedup vs baseline: 1.1335x; 1.0477x over previous
//
#include <hip/hip_runtime.h>

#define B_ 2
#define L_ 2048
#define D_ 1024
#define H_ 16
#define DH_ 64

typedef float f32x4 __attribute__((ext_vector_type(4)));
typedef __bf16 bf16x8 __attribute__((ext_vector_type(8)));

__device__ __forceinline__ ushort f2bf(float f) {
  unsigned u = __float_as_uint(f);
  u += 0x7fffu + ((u >> 16) & 1u);
  return (ushort)(u >> 16);
}
__device__ __forceinline__ float bf2f(ushort h) {
  return __uint_as_float(((unsigned)h) << 16);
}

__device__ __forceinline__ void gload_lds16(const void* g, void* l) {
  __builtin_amdgcn_global_load_lds(
      (const __attribute__((address_space(1))) unsigned*)g,
      (__attribute__((address_space(3))) unsigned*)l, 16, 0, 0);
}

__device__ __forceinline__ float gelu_f(float v) {
  return 0.5f * v * (1.0f + tanhf(0.7978845608f * (v + 0.044715f * v * v * v)));
}

// ---------------- cast f32 -> bf16, all four weights in one launch ----------------
__global__ __launch_bounds__(256) void cast_all_kernel(const float* __restrict__ w0,
                                                       const float* __restrict__ w1,
                                                       const float* __restrict__ w2,
                                                       const float* __restrict__ w3,
                                                       ushort* __restrict__ o0,
                                                       ushort* __restrict__ o1,
                                                       ushort* __restrict__ o2,
                                                       ushort* __restrict__ o3) {
  int i = blockIdx.x * 256 + threadIdx.x;
  const float* src;
  ushort* dst;
  int j = i;
  if (j < 786432) { src = w0; dst = o0; }
  else if (j < 786432 + 262144) { j -= 786432; src = w1; dst = o1; }
  else if (j < 786432 + 262144 + 1048576) { j -= 786432 + 262144; src = w2; dst = o2; }
  else { j -= 786432 + 262144 + 1048576; src = w3; dst = o3; }
  float4 v = ((const float4*)src)[j];
  ushort4 o;
  o.x = f2bf(v.x); o.y = f2bf(v.y); o.z = f2bf(v.z); o.w = f2bf(v.w);
  ((ushort4*)dst)[j] = o;
}

// ---------------- RMSNorm (T in, bf16 out), one block per row of 1024 ----------------
template <typename T>
__global__ __launch_bounds__(256) void rmsnorm_kernel(const T* __restrict__ x,
                                                      const float* __restrict__ scale,
                                                      ushort* __restrict__ out) {
  int row = blockIdx.x, t = threadIdx.x;
  float4 v;
  if constexpr (sizeof(T) == 4) {
    v = ((const float4*)((const float*)x + (size_t)row * D_))[t];
  } else {
    ushort4 u = ((const ushort4*)((const ushort*)x + (size_t)row * D_))[t];
    v.x = bf2f(u.x); v.y = bf2f(u.y); v.z = bf2f(u.z); v.w = bf2f(u.w);
  }
  float ss = v.x * v.x + v.y * v.y + v.z * v.z + v.w * v.w;
#pragma unroll
  for (int d = 1; d < 64; d <<= 1) ss += __shfl_xor(ss, d);
  __shared__ float wsum[4];
  if ((t & 63) == 0) wsum[t >> 6] = ss;
  __syncthreads();
  float tot = wsum[0] + wsum[1] + wsum[2] + wsum[3];
  float r = rsqrtf(tot * (1.0f / D_) + 1e-6f);
  float4 sc = ((const float4*)scale)[t];
  ushort4 o;
  o.x = f2bf(v.x * sc.x * r); o.y = f2bf(v.y * sc.y * r);
  o.z = f2bf(v.z * sc.z * r); o.w = f2bf(v.w * sc.w * r);
  ((ushort4*)(out + (size_t)row * D_))[t] = o;
}

// ============ 256x256 8-phase NT GEMM (m194-m201 template, plain HIP) ============
// BK=64, 8 waves (2Mx4N), 512 threads, LDS 128KB: 2 dbuf x {A,B} x 2 half-tiles
// [128 rows][64 k] bf16, chunk-XOR swizzled (chunk ^= row&7) via pre-swizzled
// gload source (rule 21). 4 phases per K-tile, phase = C-quadrant (qa,qb) in order
// (0,0)(0,1)(1,1)(1,0) so A-frags live 2 phases, B-frags reused across the tile
// (24 ds_read_b128/K-tile = minimal). Each phase stages ONE half-tile of tile t+1
// in first-read order {A0,B0,B1,A1}; counted vmcnt(4) per phase gives lag-3
// completion guarantee = exactly each half-tile's stage->first-read distance.
// lgkmcnt(0)+sched_barrier(0) before the 16-MFMA cluster (rule 18), setprio (T5).
// EPI 0: bf16 store. EPI 2: bf16 gelu.
template <int EPI, int XR, int XC>
__global__ __launch_bounds__(512, 2) void gemm256(const ushort* __restrict__ A,
                                                  const ushort* __restrict__ Bw,
                                                  void* __restrict__ Cout,
                                                  int M, int N, int K) {
  __shared__ __align__(16) ushort Als[2][2][128 * 64];
  __shared__ __align__(16) ushort Bls[2][2][128 * 64];
  const int tid = threadIdx.x;
  const int lane = tid & 63;
  const int w = tid >> 6;
  const int wm = w >> 2, wn = w & 3;
  const int fr = lane & 15, fg = lane >> 4;
  const int bid = blockIdx.y * gridDim.x + blockIdx.x;
  const int xcd = bid & 7, i0 = bid >> 3;
  const int CR = gridDim.x / XR, CC = gridDim.y / XC;
  const int rt = (xcd % XR) * CR + (i0 % CR);
  const int ct = (xcd / XR) * CC + (i0 / CR);
  const int row0 = rt * 256, col0 = ct * 256;
  const ushort* Ab = A + (size_t)row0 * K;
  const ushort* Bb = Bw + (size_t)col0 * K;
  const int srow = tid >> 3;                    // 0..63 dest row within 64-row group
  const int sxor = ((tid & 7) ^ (srow & 7)) * 8;  // pre-swizzled source col element

  f32x4 acc[8][4];
  f32x4 zero = {0.f, 0.f, 0.f, 0.f};
#pragma unroll
  for (int m = 0; m < 8; m++)
#pragma unroll
    for (int n = 0; n < 4; n++) acc[m][n] = zero;

  auto stageA = [&](int buf, int half, int kt) {
#pragma unroll
    for (int i = 0; i < 2; i++)
      gload_lds16(Ab + (size_t)(half * 128 + i * 64 + srow) * K + kt + sxor,
                  &Als[buf][half][i * 4096 + tid * 8]);
  };
  auto stageB = [&](int buf, int half, int kt) {
#pragma unroll
    for (int i = 0; i < 2; i++)
      gload_lds16(Bb + (size_t)(half * 128 + i * 64 + srow) * K + kt + sxor,
                  &Bls[buf][half][i * 4096 + tid * 8]);
  };
  const int nt = K >> 6;
  // prologue: tile 0's four half-tiles, full drain
  stageA(0, 0, 0); stageB(0, 0, 0); stageB(0, 1, 0); stageA(0, 1, 0);
  asm volatile("s_waitcnt vmcnt(0)" ::: "memory");
  __builtin_amdgcn_s_barrier();

  bf16x8 afr[4][2], b0[2][2], b1[2][2];
  for (int t = 0; t < nt; t++) {
    const int cur = t & 1, nxt = cur ^ 1;
    const int kn = (t + 1) << 6;
    const bool more = (t + 1 < nt);
    // ---------- phase 0: quadrant (qa=0, qb=0) ----------
#pragma unroll
    for (int mf = 0; mf < 4; mf++)
#pragma unroll
      for (int ks = 0; ks < 2; ks++) {
        int r = wm * 64 + mf * 16 + fr;
        afr[mf][ks] = *(const bf16x8*)&Als[cur][0][r * 64 + (((ks * 4 + fg) ^ (r & 7)) << 3)];
      }
#pragma unroll
    for (int nf = 0; nf < 2; nf++)
#pragma unroll
      for (int ks = 0; ks < 2; ks++) {
        int c = wn * 32 + nf * 16 + fr;
        b0[nf][ks] = *(const bf16x8*)&Bls[cur][0][c * 64 + (((ks * 4 + fg) ^ (c & 7)) << 3)];
      }
    if (more) stageA(nxt, 0, kn);
    asm volatile("s_waitcnt vmcnt(4)" ::: "memory");
    __builtin_amdgcn_s_barrier();
    asm volatile("s_waitcnt lgkmcnt(0)" ::: "memory");
    __builtin_amdgcn_sched_barrier(0);
    __builtin_amdgcn_s_setprio(1);
#pragma unroll
    for (int mf = 0; mf < 4; mf++)
#pragma unroll
      for (int nf = 0; nf < 2; nf++)
#pragma unroll
        for (int ks = 0; ks < 2; ks++)
          acc[mf][nf] =
              __builtin_amdgcn_mfma_f32_16x16x32_bf16(afr[mf][ks], b0[nf][ks], acc[mf][nf], 0, 0, 0);
    __builtin_amdgcn_s_setprio(0);
    __builtin_amdgcn_s_barrier();
    // ---------- phase 1: quadrant (qa=0, qb=1) ----------
#pragma unroll
    for (int nf = 0; nf < 2; nf++)
#pragma unroll
      for (int ks = 0; ks < 2; ks++) {
        int c = wn * 32 + nf * 16 + fr;
        b1[nf][ks] = *(const bf16x8*)&Bls[cur][1][c * 64 + (((ks * 4 + fg) ^ (c & 7)) << 3)];
      }
    if (more) stageB(nxt, 0, kn);
    asm volatile("s_waitcnt vmcnt(4)" ::: "memory");
    __builtin_amdgcn_s_barrier();
    asm volatile("s_waitcnt lgkmcnt(0)" ::: "memory");
    __builtin_amdgcn_sched_barrier(0);
    __builtin_amdgcn_s_setprio(1);
#pragma unroll
    for (int mf = 0; mf < 4; mf++)
#pragma unroll
      for (int nf = 0; nf < 2; nf++)
#pragma unroll
        for (int ks = 0; ks < 2; ks++)
          acc[mf][2 + nf] =
              __builtin_amdgcn_mfma_f32_16x16x32_bf16(afr[mf][ks], b1[nf][ks], acc[mf][2 + nf], 0, 0, 0);
    __builtin_amdgcn_s_setprio(0);
    __builtin_amdgcn_s_barrier();
    // ---------- phase 2: quadrant (qa=1, qb=1) ----------
#pragma unroll
    for (int mf = 0; mf < 4; mf++)
#pragma unroll
      for (int ks = 0; ks < 2; ks++) {
        int r = wm * 64 + mf * 16 + fr;
        afr[mf][ks] = *(const bf16x8*)&Als[cur][1][r * 64 + (((ks * 4 + fg) ^ (r & 7)) << 3)];
      }
    if (more) stageB(nxt, 1, kn);
    asm volatile("s_waitcnt vmcnt(4)" ::: "memory");
    __builtin_amdgcn_s_barrier();
    asm volatile("s_waitcnt lgkmcnt(0)" ::: "memory");
    __builtin_amdgcn_sched_barrier(0);
    __builtin_amdgcn_s_setprio(1);
#pragma unroll
    for (int mf = 0; mf < 4; mf++)
#pragma unroll
      for (int nf = 0; nf < 2; nf++)
#pragma unroll
        for (int ks = 0; ks < 2; ks++)
          acc[4 + mf][2 + nf] =
              __builtin_amdgcn_mfma_f32_16x16x32_bf16(afr[mf][ks], b1[nf][ks], acc[4 + mf][2 + nf], 0, 0, 0);
    __builtin_amdgcn_s_setprio(0);
    __builtin_amdgcn_s_barrier();
    // ---------- phase 3: quadrant (qa=1, qb=0) ----------
    if (more) stageA(nxt, 1, kn);
    asm volatile("s_waitcnt vmcnt(4)" ::: "memory");
    __builtin_amdgcn_s_barrier();
    asm volatile("s_waitcnt lgkmcnt(0)" ::: "memory");
    __builtin_amdgcn_sched_barrier(0);
    __builtin_amdgcn_s_setprio(1);
#pragma unroll
    for (int mf = 0; mf < 4; mf++)
#pragma unroll
      for (int nf = 0; nf < 2; nf++)
#pragma unroll
        for (int ks = 0; ks < 2; ks++)
          acc[4 + mf][nf] =
              __builtin_amdgcn_mfma_f32_16x16x32_bf16(afr[mf][ks], b0[nf][ks], acc[4 + mf][nf], 0, 0, 0);
    __builtin_amdgcn_s_setprio(0);
    __builtin_amdgcn_s_barrier();
  }
  // epilogue
  const int orow = row0 + wm * 64 + fg * 4;
  const int ocol = col0 + wn * 32 + fr;
#pragma unroll
  for (int am = 0; am < 8; am++) {
#pragma unroll
    for (int j = 0; j < 4; j++) {
      int r = orow + (am >> 2) * 128 + (am & 3) * 16 + j;
#pragma unroll
      for (int an = 0; an < 4; an++) {
        int cidx = ocol + (an >> 1) * 128 + (an & 1) * 16;
        size_t idx = (size_t)r * N + cidx;
        float v = acc[am][an][j];
        if (EPI == 0) {
          ((ushort*)Cout)[idx] = f2bf(v);
        } else {
          ((ushort*)Cout)[idx] = f2bf(gelu_f(v));
        }
      }
    }
  }
}

// ---------------- 128/64 NT GEMM (R12 ring structure) for out/down ----------------
template <int EPI, int BM, int BN, int DEPTH, int XR, int XC, bool CTFAST>
__global__ __launch_bounds__(256) void gemm_nt(const ushort* __restrict__ A,
                                               const ushort* __restrict__ Bw,
                                               void* __restrict__ Cout,
                                               const void* __restrict__ resid,
                                               int M, int N, int K, int Klen) {
  constexpr int WROWS = BM / 2, WCOLS = BN / 2;
  constexpr int MR = WROWS / 16, NR = WCOLS / 16;
  constexpr int ALOADS = BM / 64, BLOADS = BN / 64;
  constexpr int NLOADS = ALOADS + BLOADS;
  __shared__ __align__(16) ushort Als[DEPTH][BM * 32];
  __shared__ __align__(16) ushort Bls[DEPTH][BN * 32];
  const int tid = threadIdx.x;
  const int lane = tid & 63;
  const int w = tid >> 6;
  const int wr = w >> 1, wc = w & 1;
  const int bid = blockIdx.y * gridDim.x + blockIdx.x;
  const int xcd = bid & 7;
  const int i0 = bid >> 3;
  const int CR = gridDim.x / XR, CC = gridDim.y / XC;
  int rt, ct;
  if constexpr (CTFAST) {
    rt = (xcd % XR) * CR + (i0 / CC);
    ct = (xcd / XR) * CC + (i0 % CC);
  } else {
    rt = (xcd % XR) * CR + (i0 % CR);
    ct = (xcd / XR) * CC + (i0 / CR);
  }
  const int row0 = rt * BM;
  const int col0 = ct * BN;
  const int koff = blockIdx.z * Klen;
  const ushort* Ab = A + (size_t)row0 * K + koff;
  const ushort* Bb = Bw + (size_t)col0 * K + koff;
  const int sr = tid >> 2;
  const int scA = (((tid & 3) ^ ((tid >> 3) & 3)) * 8);
  const int fr = lane & 15;
  const int fg = lane >> 4;
  f32x4 zero = {0.f, 0.f, 0.f, 0.f};
  f32x4 acc[MR][NR];
#pragma unroll
  for (int m = 0; m < MR; m++)
#pragma unroll
    for (int n = 0; n < NR; n++) acc[m][n] = zero;

  auto stage = [&](int slot, int kt) {
#pragma unroll
    for (int i2 = 0; i2 < ALOADS; i2++)
      gload_lds16(Ab + (size_t)(sr + 64 * i2) * K + kt + scA, &Als[slot][i2 * 2048 + tid * 8]);
#pragma unroll
    for (int i2 = 0; i2 < BLOADS; i2++)
      gload_lds16(Bb + (size_t)(sr + 64 * i2) * K + kt + scA, &Bls[slot][i2 * 2048 + tid * 8]);
  };
  const int nt = Klen >> 5;
#pragma unroll
  for (int p = 0; p < DEPTH - 1; p++) stage(p, p << 5);
  int cur = 0, sbuf = DEPTH - 1;
  for (int t = 0; t < nt; t++) {
    const int ahead = nt - 1 - t;
    if constexpr (DEPTH == 3) {
      if (ahead >= 1) asm volatile("s_waitcnt vmcnt(%0)" ::"i"(NLOADS) : "memory");
      else            asm volatile("s_waitcnt vmcnt(0)" ::: "memory");
    } else if constexpr (DEPTH == 4) {
      if (ahead >= 2)      asm volatile("s_waitcnt vmcnt(%0)" ::"i"(2 * NLOADS) : "memory");
      else if (ahead == 1) asm volatile("s_waitcnt vmcnt(%0)" ::"i"(NLOADS) : "memory");
      else                 asm volatile("s_waitcnt vmcnt(0)" ::: "memory");
    } else {
      if (ahead >= 3)      asm volatile("s_waitcnt vmcnt(%0)" ::"i"(3 * NLOADS) : "memory");
      else if (ahead == 2) asm volatile("s_waitcnt vmcnt(%0)" ::"i"(2 * NLOADS) : "memory");
      else if (ahead == 1) asm volatile("s_waitcnt vmcnt(%0)" ::"i"(NLOADS) : "memory");
      else                 asm volatile("s_waitcnt vmcnt(0)" ::: "memory");
    }
    __builtin_amdgcn_s_barrier();
    if (t + DEPTH - 1 < nt) {
      stage(sbuf, (t + DEPTH - 1) << 5);
      sbuf = (sbuf == DEPTH - 1) ? 0 : sbuf + 1;
    }
    bf16x8 af[MR], bfr[NR];
#pragma unroll
    for (int m = 0; m < MR; m++) {
      int rA = wr * WROWS + m * 16 + fr;
      af[m] = *(const bf16x8*)&Als[cur][rA * 32 + ((fg ^ ((rA >> 1) & 3)) << 3)];
    }
#pragma unroll
    for (int n = 0; n < NR; n++) {
      int rB = wc * WCOLS + n * 16 + fr;
      bfr[n] = *(const bf16x8*)&Bls[cur][rB * 32 + ((fg ^ ((rB >> 1) & 3)) << 3)];
    }
#pragma unroll
    for (int m = 0; m < MR; m++)
#pragma unroll
      for (int n = 0; n < NR; n++)
        acc[m][n] = __builtin_amdgcn_mfma_f32_16x16x32_bf16(af[m], bfr[n], acc[m][n], 0, 0, 0);
    cur = (cur == DEPTH - 1) ? 0 : cur + 1;
  }
  const int orow = row0 + wr * WROWS + fg * 4;
  const int ocol = col0 + wc * WCOLS + fr;
  float* Pz = (float*)Cout + (size_t)blockIdx.z * M * N;
#pragma unroll
  for (int m = 0; m < MR; m++) {
#pragma unroll
    for (int j = 0; j < 4; j++) {
      int r = orow + m * 16 + j;
#pragma unroll
      for (int n = 0; n < NR; n++) {
        int cidx = ocol + n * 16;
        size_t idx = (size_t)r * N + cidx;
        float v = acc[m][n][j];
        if (EPI == 0) {
          ((ushort*)Cout)[idx] = f2bf(v);
        } else if (EPI == 1) {
          ((ushort*)Cout)[idx] = f2bf(((const float*)resid)[idx] + v);
        } else if (EPI == 2) {
          ((ushort*)Cout)[idx] = f2bf(gelu_f(v));
        } else if (EPI == 3) {
          ((float*)Cout)[idx] = bf2f(((const ushort*)resid)[idx]) + v;
        } else {
          Pz[idx] = v;
        }
      }
    }
  }
}

// ---------------- split-K reduce: out = bf16resid + P0 + P1 ----------------
__global__ __launch_bounds__(256) void reduce_down_kernel(const float* __restrict__ P0,
                                                          const float* __restrict__ P1,
                                                          const ushort* __restrict__ residb,
                                                          float* __restrict__ out) {
  int i = blockIdx.x * 256 + threadIdx.x;
  float4 a = ((const float4*)P0)[i];
  float4 b = ((const float4*)P1)[i];
  ushort4 r = ((const ushort4*)residb)[i];
  float4 o;
  o.x = a.x + b.x + bf2f(r.x);
  o.y = a.y + b.y + bf2f(r.y);
  o.z = a.z + b.z + bf2f(r.z);
  o.w = a.w + b.w + bf2f(r.w);
  ((float4*)out)[i] = o;
}

// ---------------- RoPE + cosine-sim scaling ----------------
__global__ __launch_bounds__(256) void rope_kernel(const ushort* __restrict__ qkv,
                                                   const float* __restrict__ pos,
                                                   const float* __restrict__ pos_orig,
                                                   const float* __restrict__ timep,
                                                   const float* __restrict__ qk_scale,
                                                   ushort* __restrict__ qr,
                                                   ushort* __restrict__ kr) {
  int gw = (blockIdx.x * 256 + threadIdx.x) >> 6;
  int lane = threadIdx.x & 63;
  int h = gw & 15;
  int row = gw >> 4;
  int b = row >> 11;
  int l = row & (L_ - 1);
  float qv = bf2f(qkv[(size_t)row * 3072 + h * 64 + lane]);
  float kv = bf2f(qkv[(size_t)row * 3072 + 1024 + h * 64 + lane]);
  float c = 1.0f, s = 0.0f;
  if (lane < 50) {
    int idx = lane < 25 ? lane : lane - 25;
    int sg = idx / 5, d = idx % 5;
    int fi = d * 16 + h;
    float th;
    if (sg == 4) {
      th = timep[row] * __expf(-(float)fi * 0.05756462732485115f);
    } else {
      float fr = 3.14159265358979323846f * __expf((float)fi * 0.028782313662425575f);
      const float* psrc = (sg == 0 || sg == 2) ? pos_orig : pos;
      int comp = (sg < 2) ? 1 : 0;
      th = (2.0f * psrc[(size_t)row * 2 + comp] - 1.0f) * fr;
    }
    s = sinf(th);
    c = cosf(th);
  }
  int partner = lane < 25 ? lane + 25 : lane - 25;
  float qp = __shfl(qv, partner, 64);
  float kp = __shfl(kv, partner, 64);
  float yq, yk;
  if (lane < 25) { yq = qv * c - qp * s; yk = kv * c - kp * s; }
  else if (lane < 50) { yq = qv * c + qp * s; yk = kv * c + kp * s; }
  else { yq = qv; yk = kv; }
  float sq = yq * yq, sk = yk * yk;
#pragma unroll
  for (int d = 1; d < 64; d <<= 1) { sq += __shfl_xor(sq, d); sk += __shfl_xor(sk, d); }
  float scl = sqrtf(qk_scale[h]);
  float qo = yq * scl * rsqrtf(sq + 1e-6f);
  float ko = yk * scl * rsqrtf(sk + 1e-6f);
  size_t o = ((size_t)(b * 16 + h) * L_ + l) * 64 + lane;
  qr[o] = f2bf(qo);
  kr[o] = f2bf(ko);
}

// ---------------- V transpose ----------------
__global__ __launch_bounds__(256) void vtrans_kernel(const ushort* __restrict__ qkv,
                                                     ushort* __restrict__ vT) {
  __shared__ __align__(16) ushort tile[64][72];
  int t = threadIdx.x;
  int lt = blockIdx.x;
  int bh = blockIdx.y;
  int b = bh >> 4, h = bh & 15;
  int r = t >> 3, c0 = (t & 7) * 8;
#pragma unroll
  for (int half = 0; half < 2; half++) {
    const ushort* src =
        qkv + (size_t)(b * L_ + lt * 64 + r + half * 32) * 3072 + 2048 + h * 64 + c0;
    *(uint4*)&tile[r + half * 32][c0] = *(const uint4*)src;
  }
  __syncthreads();
#pragma unroll
  for (int half = 0; half < 2; half++) {
    int dh = r + half * 32;
    unsigned p0 = (unsigned)tile[c0 + 0][dh] | ((unsigned)tile[c0 + 1][dh] << 16);
    unsigned p1 = (unsigned)tile[c0 + 2][dh] | ((unsigned)tile[c0 + 3][dh] << 16);
    unsigned p2 = (unsigned)tile[c0 + 4][dh] | ((unsigned)tile[c0 + 5][dh] << 16);
    unsigned p3 = (unsigned)tile[c0 + 6][dh] | ((unsigned)tile[c0 + 7][dh] << 16);
    uint4 o; o.x = p0; o.y = p1; o.z = p2; o.w = p3;
    *(uint4*)&vT[((size_t)bh * 64 + dh) * L_ + lt * 64 + c0] = o;
  }
}

// ---------------- Flash attention (R12 structure, unchanged) ----------------
__global__ __launch_bounds__(256) void attn_kernel(const ushort* __restrict__ qr,
                                                   const ushort* __restrict__ kr,
                                                   const ushort* __restrict__ vT,
                                                   ushort* __restrict__ attnb) {
  __shared__ __align__(16) ushort Kls[2][64 * 64];
  __shared__ __align__(16) ushort Vls[2][64 * 64];
  __shared__ __align__(16) ushort Pls[4][16 * 64];
  const int tid = threadIdx.x, lane = tid & 63, w = tid >> 6;
  const int bid = blockIdx.x;
  const int qp = (bid >> 3) & 15;
  const int bh = (bid & 7) | ((bid >> 7) << 3);
  const int b = bh >> 4;
  const int fr = lane & 15, fg = lane >> 4;
  const ushort* Qb0 = qr + ((size_t)bh * L_ + qp * 128 + w * 16) * 64;
  const ushort* Qb1 = Qb0 + 64 * 64;
  bf16x8 qf0[2], qf1[2];
#pragma unroll
  for (int c = 0; c < 2; c++) {
    qf0[c] = *(const bf16x8*)(Qb0 + fr * 64 + c * 32 + fg * 8);
    qf1[c] = *(const bf16x8*)(Qb1 + fr * 64 + c * 32 + fg * 8);
  }
  const ushort ob[8] = {0x3F80, 0x3F80, 0x3F80, 0x3F80, 0x3F80, 0x3F80, 0x3F80, 0x3F80};
  const bf16x8 ones = *(const bf16x8*)ob;
  f32x4 zero = {0.f, 0.f, 0.f, 0.f};
  f32x4 accO0[4], accO1[4], acc1_0 = zero, acc1_1 = zero;
#pragma unroll
  for (int n = 0; n < 4; n++) { accO0[n] = zero; accO1[n] = zero; }
  const int sr = tid >> 3;
  const int scz = (((tid & 7) ^ (sr & 7)) * 8);
  auto stage = [&](int buf, int kt) {
    gload_lds16(kr + ((size_t)bh * L_ + kt + sr) * 64 + scz, &Kls[buf][tid * 8]);
    gload_lds16(kr + ((size_t)bh * L_ + kt + 32 + sr) * 64 + scz, &Kls[buf][2048 + tid * 8]);
    gload_lds16(vT + ((size_t)bh * 64 + sr) * L_ + kt + scz, &Vls[buf][tid * 8]);
    gload_lds16(vT + ((size_t)bh * 64 + 32 + sr) * L_ + kt + scz, &Vls[buf][2048 + tid * 8]);
  };
  stage(0, 0);
  int cur = 0;
  for (int t = 0; t < (L_ >> 6); t++) {
    asm volatile("s_waitcnt vmcnt(0)" ::: "memory");
    __builtin_amdgcn_s_barrier();
    __builtin_amdgcn_sched_barrier(0);
    if (t + 1 < (L_ >> 6)) stage(cur ^ 1, (t + 1) << 6);
#pragma unroll
    for (int qs = 0; qs < 2; qs++) {
      const bf16x8* qf = qs ? qf1 : qf0;
      f32x4* accO = qs ? accO1 : accO0;
      f32x4& acc1 = qs ? acc1_1 : acc1_0;
      f32x4 sv[4];
#pragma unroll
      for (int n = 0; n < 4; n++) sv[n] = zero;
      __builtin_amdgcn_s_setprio(1);
#pragma unroll
      for (int c = 0; c < 2; c++) {
#pragma unroll
        for (int n = 0; n < 4; n++) {
          bf16x8 kf =
              *(const bf16x8*)&Kls[cur][(n * 16 + fr) * 64 + (((c * 4 + fg) ^ (fr & 7)) << 3)];
          sv[n] = __builtin_amdgcn_mfma_f32_16x16x32_bf16(qf[c], kf, sv[n], 0, 0, 0);
        }
      }
      __builtin_amdgcn_s_setprio(0);
#pragma unroll
      for (int j = 0; j < 4; j++) {
        int row = fg * 4 + j;
        int rbase = row * 64;
        int rx = row & 7;
#pragma unroll
        for (int n = 0; n < 4; n++) {
          float p = __builtin_amdgcn_exp2f(
              fmaf(sv[n][j], 1.4426950408889634f, -17.31234049066756f));
          int chunk = 2 * n + (fr >> 3);
          Pls[w][rbase + ((chunk ^ rx) << 3) + (fr & 7)] =
              (ushort)(__float_as_uint(p) >> 16);
        }
      }
      __builtin_amdgcn_s_setprio(1);
#pragma unroll
      for (int c = 0; c < 2; c++) {
        bf16x8 pa = *(const bf16x8*)&Pls[w][fr * 64 + (((c * 4 + fg) ^ (fr & 7)) << 3)];
#pragma unroll
        for (int n = 0; n < 4; n++) {
          bf16x8 vb =
              *(const bf16x8*)&Vls[cur][(n * 16 + fr) * 64 + (((c * 4 + fg) ^ (fr & 7)) << 3)];
          accO[n] = __builtin_amdgcn_mfma_f32_16x16x32_bf16(pa, vb, accO[n], 0, 0, 0);
        }
        acc1 = __builtin_amdgcn_mfma_f32_16x16x32_bf16(pa, ones, acc1, 0, 0, 0);
      }
      __builtin_amdgcn_s_setprio(0);
    }
    cur ^= 1;
  }
#pragma unroll
  for (int qs = 0; qs < 2; qs++) {
    const f32x4* accO = qs ? accO1 : accO0;
    const f32x4& acc1 = qs ? acc1_1 : acc1_0;
    float inv[4];
#pragma unroll
    for (int j = 0; j < 4; j++) inv[j] = 1.0f / acc1[j];
#pragma unroll
    for (int n = 0; n < 4; n++) {
#pragma unroll
      for (int j = 0; j < 4; j++) {
        float o = accO[n][j] * inv[j];
        int qrow = qp * 128 + qs * 64 + w * 16 + fg * 4 + j;
        int dh = fr + n * 16;
        attnb[(size_t)(b * L_ + qrow) * 1024 + (bh & 15) * 64 + dh] = f2bf(o);
      }
    }
  }
}

extern "C" void kernel_launch(void* const* d_in, const int* in_sizes, int n_in,
                              void* d_out, int out_size, void* d_ws, size_t ws_size,
                              hipStream_t stream) {
  const float* x = (const float*)d_in[0];
  const float* pos = (const float*)d_in[1];
  const float* pos_orig = (const float*)d_in[2];
  const float* timep = (const float*)d_in[3];
  const float* w_qkv = (const float*)d_in[4];
  const float* w_out = (const float*)d_in[5];
  const float* w_up = (const float*)d_in[6];
  const float* w_down = (const float*)d_in[7];
  const float* norm1 = (const float*)d_in[8];
  const float* norm2 = (const float*)d_in[9];
  const float* qk_scale = (const float*)d_in[10];
  float* out = (float*)d_out;
  char* ws = (char*)d_ws;
  size_t off = 0;
  auto alloc = [&](size_t bytes) {
    void* p = ws + off;
    off += bytes;
    return p;
  };
  ushort* xn = (ushort*)alloc(8ull << 20);
  ushort* qkvb = (ushort*)alloc(32ull << 20);
  ushort* qrb = (ushort*)alloc(8ull << 20);
  ushort* krb = (ushort*)alloc(8ull << 20);
  ushort* vTb = (ushort*)alloc(8ull << 20);
  ushort* attnb = (ushort*)alloc(8ull << 20);
  ushort* x1b = (ushort*)alloc(8ull << 20);
  ushort* wqkvb = (ushort*)alloc(6ull << 20);
  ushort* woutb = (ushort*)alloc(2ull << 20);
  ushort* wupb = (ushort*)alloc(8ull << 20);
  ushort* wdownb = (ushort*)alloc(8ull << 20);
  float* Ppart = (float*)qrb;

  cast_all_kernel<<<12288, 256, 0, stream>>>(w_qkv, w_out, w_up, w_down,
                                             wqkvb, woutb, wupb, wdownb);

  rmsnorm_kernel<float><<<4096, 256, 0, stream>>>(x, norm1, xn);
  // qkv: 256^2 8-phase (grid 16x12, 512 threads)
  gemm256<0, 4, 2><<<dim3(16, 12), 512, 0, stream>>>(xn, wqkvb, qkvb, 4096, 3072, 1024);
  rope_kernel<<<16384, 256, 0, stream>>>(qkvb, pos, pos_orig, timep, qk_scale, qrb, krb);
  vtrans_kernel<<<dim3(32, 32), 256, 0, stream>>>(qkvb, vTb);
  attn_kernel<<<512, 256, 0, stream>>>(qrb, krb, vTb, attnb);
  // out: 64x64 depth5 grid(64,16) (2 blocks/CU)
  gemm_nt<1, 64, 64, 5, 4, 2, false><<<dim3(64, 16), 256, 0, stream>>>(
      attnb, woutb, x1b, x, 4096, 1024, 1024, 1024);
  rmsnorm_kernel<ushort><<<4096, 256, 0, stream>>>(x1b, norm2, xn);
  // up: 256^2 8-phase + fused gelu (grid 16x16)
  gemm256<2, 4, 2><<<dim3(16, 16), 512, 0, stream>>>(xn, wupb, qkvb, 4096, 4096, 1024);
  // down: split-K=2, 128x128 DEPTH=4
  gemm_nt<4, 128, 128, 4, 4, 2, true><<<dim3(32, 8, 2), 256, 0, stream>>>(
      qkvb, wdownb, Ppart, nullptr, 4096, 1024, 4096, 2048);
  reduce_down_kernel<<<4096, 256, 0, stream>>>(Ppart, Ppart + (4u << 20), x1b, out);
}

// Round 15
// 266.866 us; speedup vs baseline: 1.1477x; 1.0125x over previous
//
#include <hip/hip_runtime.h>

#define B_ 2
#define L_ 2048
#define D_ 1024
#define H_ 16
#define DH_ 64

typedef float f32x4 __attribute__((ext_vector_type(4)));
typedef __bf16 bf16x8 __attribute__((ext_vector_type(8)));

__device__ __forceinline__ ushort f2bf(float f) {
  unsigned u = __float_as_uint(f);
  u += 0x7fffu + ((u >> 16) & 1u);
  return (ushort)(u >> 16);
}
__device__ __forceinline__ float bf2f(ushort h) {
  return __uint_as_float(((unsigned)h) << 16);
}

__device__ __forceinline__ void gload_lds16(const void* g, void* l) {
  __builtin_amdgcn_global_load_lds(
      (const __attribute__((address_space(1))) unsigned*)g,
      (__attribute__((address_space(3))) unsigned*)l, 16, 0, 0);
}

__device__ __forceinline__ float gelu_f(float v) {
  return 0.5f * v * (1.0f + tanhf(0.7978845608f * (v + 0.044715f * v * v * v)));
}

// ---------------- cast f32 -> bf16, all four weights in one launch ----------------
__global__ __launch_bounds__(256) void cast_all_kernel(const float* __restrict__ w0,
                                                       const float* __restrict__ w1,
                                                       const float* __restrict__ w2,
                                                       const float* __restrict__ w3,
                                                       ushort* __restrict__ o0,
                                                       ushort* __restrict__ o1,
                                                       ushort* __restrict__ o2,
                                                       ushort* __restrict__ o3) {
  int i = blockIdx.x * 256 + threadIdx.x;
  const float* src;
  ushort* dst;
  int j = i;
  if (j < 786432) { src = w0; dst = o0; }
  else if (j < 786432 + 262144) { j -= 786432; src = w1; dst = o1; }
  else if (j < 786432 + 262144 + 1048576) { j -= 786432 + 262144; src = w2; dst = o2; }
  else { j -= 786432 + 262144 + 1048576; src = w3; dst = o3; }
  float4 v = ((const float4*)src)[j];
  ushort4 o;
  o.x = f2bf(v.x); o.y = f2bf(v.y); o.z = f2bf(v.z); o.w = f2bf(v.w);
  ((ushort4*)dst)[j] = o;
}

// ---------------- RMSNorm (T in, bf16 out), one block per row of 1024 ----------------
template <typename T>
__global__ __launch_bounds__(256) void rmsnorm_kernel(const T* __restrict__ x,
                                                      const float* __restrict__ scale,
                                                      ushort* __restrict__ out) {
  int row = blockIdx.x, t = threadIdx.x;
  float4 v;
  if constexpr (sizeof(T) == 4) {
    v = ((const float4*)((const float*)x + (size_t)row * D_))[t];
  } else {
    ushort4 u = ((const ushort4*)((const ushort*)x + (size_t)row * D_))[t];
    v.x = bf2f(u.x); v.y = bf2f(u.y); v.z = bf2f(u.z); v.w = bf2f(u.w);
  }
  float ss = v.x * v.x + v.y * v.y + v.z * v.z + v.w * v.w;
#pragma unroll
  for (int d = 1; d < 64; d <<= 1) ss += __shfl_xor(ss, d);
  __shared__ float wsum[4];
  if ((t & 63) == 0) wsum[t >> 6] = ss;
  __syncthreads();
  float tot = wsum[0] + wsum[1] + wsum[2] + wsum[3];
  float r = rsqrtf(tot * (1.0f / D_) + 1e-6f);
  float4 sc = ((const float4*)scale)[t];
  ushort4 o;
  o.x = f2bf(v.x * sc.x * r); o.y = f2bf(v.y * sc.y * r);
  o.z = f2bf(v.z * sc.z * r); o.w = f2bf(v.w * sc.w * r);
  ((ushort4*)(out + (size_t)row * D_))[t] = o;
}

// ============ 256x256 8-phase NT GEMM (m194-m201 template, plain HIP) ============
template <int EPI, int XR, int XC>
__global__ __launch_bounds__(512, 2) void gemm256(const ushort* __restrict__ A,
                                                  const ushort* __restrict__ Bw,
                                                  void* __restrict__ Cout,
                                                  int M, int N, int K) {
  __shared__ __align__(16) ushort Als[2][2][128 * 64];
  __shared__ __align__(16) ushort Bls[2][2][128 * 64];
  const int tid = threadIdx.x;
  const int lane = tid & 63;
  const int w = tid >> 6;
  const int wm = w >> 2, wn = w & 3;
  const int fr = lane & 15, fg = lane >> 4;
  const int bid = blockIdx.y * gridDim.x + blockIdx.x;
  const int xcd = bid & 7, i0 = bid >> 3;
  const int CR = gridDim.x / XR, CC = gridDim.y / XC;
  const int rt = (xcd % XR) * CR + (i0 % CR);
  const int ct = (xcd / XR) * CC + (i0 / CR);
  const int row0 = rt * 256, col0 = ct * 256;
  const ushort* Ab = A + (size_t)row0 * K;
  const ushort* Bb = Bw + (size_t)col0 * K;
  const int srow = tid >> 3;
  const int sxor = ((tid & 7) ^ (srow & 7)) * 8;

  f32x4 acc[8][4];
  f32x4 zero = {0.f, 0.f, 0.f, 0.f};
#pragma unroll
  for (int m = 0; m < 8; m++)
#pragma unroll
    for (int n = 0; n < 4; n++) acc[m][n] = zero;

  auto stageA = [&](int buf, int half, int kt) {
#pragma unroll
    for (int i = 0; i < 2; i++)
      gload_lds16(Ab + (size_t)(half * 128 + i * 64 + srow) * K + kt + sxor,
                  &Als[buf][half][i * 4096 + tid * 8]);
  };
  auto stageB = [&](int buf, int half, int kt) {
#pragma unroll
    for (int i = 0; i < 2; i++)
      gload_lds16(Bb + (size_t)(half * 128 + i * 64 + srow) * K + kt + sxor,
                  &Bls[buf][half][i * 4096 + tid * 8]);
  };
  const int nt = K >> 6;
  stageA(0, 0, 0); stageB(0, 0, 0); stageB(0, 1, 0); stageA(0, 1, 0);
  asm volatile("s_waitcnt vmcnt(0)" ::: "memory");
  __builtin_amdgcn_s_barrier();

  bf16x8 afr[4][2], b0[2][2], b1[2][2];
  for (int t = 0; t < nt; t++) {
    const int cur = t & 1, nxt = cur ^ 1;
    const int kn = (t + 1) << 6;
    const bool more = (t + 1 < nt);
    // phase 0: (0,0)
#pragma unroll
    for (int mf = 0; mf < 4; mf++)
#pragma unroll
      for (int ks = 0; ks < 2; ks++) {
        int r = wm * 64 + mf * 16 + fr;
        afr[mf][ks] = *(const bf16x8*)&Als[cur][0][r * 64 + (((ks * 4 + fg) ^ (r & 7)) << 3)];
      }
#pragma unroll
    for (int nf = 0; nf < 2; nf++)
#pragma unroll
      for (int ks = 0; ks < 2; ks++) {
        int c = wn * 32 + nf * 16 + fr;
        b0[nf][ks] = *(const bf16x8*)&Bls[cur][0][c * 64 + (((ks * 4 + fg) ^ (c & 7)) << 3)];
      }
    if (more) stageA(nxt, 0, kn);
    asm volatile("s_waitcnt vmcnt(4)" ::: "memory");
    __builtin_amdgcn_s_barrier();
    asm volatile("s_waitcnt lgkmcnt(0)" ::: "memory");
    __builtin_amdgcn_sched_barrier(0);
    __builtin_amdgcn_s_setprio(1);
#pragma unroll
    for (int mf = 0; mf < 4; mf++)
#pragma unroll
      for (int nf = 0; nf < 2; nf++)
#pragma unroll
        for (int ks = 0; ks < 2; ks++)
          acc[mf][nf] =
              __builtin_amdgcn_mfma_f32_16x16x32_bf16(afr[mf][ks], b0[nf][ks], acc[mf][nf], 0, 0, 0);
    __builtin_amdgcn_s_setprio(0);
    __builtin_amdgcn_s_barrier();
    // phase 1: (0,1)
#pragma unroll
    for (int nf = 0; nf < 2; nf++)
#pragma unroll
      for (int ks = 0; ks < 2; ks++) {
        int c = wn * 32 + nf * 16 + fr;
        b1[nf][ks] = *(const bf16x8*)&Bls[cur][1][c * 64 + (((ks * 4 + fg) ^ (c & 7)) << 3)];
      }
    if (more) stageB(nxt, 0, kn);
    asm volatile("s_waitcnt vmcnt(4)" ::: "memory");
    __builtin_amdgcn_s_barrier();
    asm volatile("s_waitcnt lgkmcnt(0)" ::: "memory");
    __builtin_amdgcn_sched_barrier(0);
    __builtin_amdgcn_s_setprio(1);
#pragma unroll
    for (int mf = 0; mf < 4; mf++)
#pragma unroll
      for (int nf = 0; nf < 2; nf++)
#pragma unroll
        for (int ks = 0; ks < 2; ks++)
          acc[mf][2 + nf] =
              __builtin_amdgcn_mfma_f32_16x16x32_bf16(afr[mf][ks], b1[nf][ks], acc[mf][2 + nf], 0, 0, 0);
    __builtin_amdgcn_s_setprio(0);
    __builtin_amdgcn_s_barrier();
    // phase 2: (1,1)
#pragma unroll
    for (int mf = 0; mf < 4; mf++)
#pragma unroll
      for (int ks = 0; ks < 2; ks++) {
        int r = wm * 64 + mf * 16 + fr;
        afr[mf][ks] = *(const bf16x8*)&Als[cur][1][r * 64 + (((ks * 4 + fg) ^ (r & 7)) << 3)];
      }
    if (more) stageB(nxt, 1, kn);
    asm volatile("s_waitcnt vmcnt(4)" ::: "memory");
    __builtin_amdgcn_s_barrier();
    asm volatile("s_waitcnt lgkmcnt(0)" ::: "memory");
    __builtin_amdgcn_sched_barrier(0);
    __builtin_amdgcn_s_setprio(1);
#pragma unroll
    for (int mf = 0; mf < 4; mf++)
#pragma unroll
      for (int nf = 0; nf < 2; nf++)
#pragma unroll
        for (int ks = 0; ks < 2; ks++)
          acc[4 + mf][2 + nf] =
              __builtin_amdgcn_mfma_f32_16x16x32_bf16(afr[mf][ks], b1[nf][ks], acc[4 + mf][2 + nf], 0, 0, 0);
    __builtin_amdgcn_s_setprio(0);
    __builtin_amdgcn_s_barrier();
    // phase 3: (1,0)
    if (more) stageA(nxt, 1, kn);
    asm volatile("s_waitcnt vmcnt(4)" ::: "memory");
    __builtin_amdgcn_s_barrier();
    asm volatile("s_waitcnt lgkmcnt(0)" ::: "memory");
    __builtin_amdgcn_sched_barrier(0);
    __builtin_amdgcn_s_setprio(1);
#pragma unroll
    for (int mf = 0; mf < 4; mf++)
#pragma unroll
      for (int nf = 0; nf < 2; nf++)
#pragma unroll
        for (int ks = 0; ks < 2; ks++)
          acc[4 + mf][nf] =
              __builtin_amdgcn_mfma_f32_16x16x32_bf16(afr[mf][ks], b0[nf][ks], acc[4 + mf][nf], 0, 0, 0);
    __builtin_amdgcn_s_setprio(0);
    __builtin_amdgcn_s_barrier();
  }
  const int orow = row0 + wm * 64 + fg * 4;
  const int ocol = col0 + wn * 32 + fr;
#pragma unroll
  for (int am = 0; am < 8; am++) {
#pragma unroll
    for (int j = 0; j < 4; j++) {
      int r = orow + (am >> 2) * 128 + (am & 3) * 16 + j;
#pragma unroll
      for (int an = 0; an < 4; an++) {
        int cidx = ocol + (an >> 1) * 128 + (an & 1) * 16;
        size_t idx = (size_t)r * N + cidx;
        float v = acc[am][an][j];
        if (EPI == 0) {
          ((ushort*)Cout)[idx] = f2bf(v);
        } else {
          ((ushort*)Cout)[idx] = f2bf(gelu_f(v));
        }
      }
    }
  }
}

// ---------------- 128/64 NT GEMM (ring structure) for out/down ----------------
template <int EPI, int BM, int BN, int DEPTH, int XR, int XC, bool CTFAST>
__global__ __launch_bounds__(256) void gemm_nt(const ushort* __restrict__ A,
                                               const ushort* __restrict__ Bw,
                                               void* __restrict__ Cout,
                                               const void* __restrict__ resid,
                                               int M, int N, int K, int Klen) {
  constexpr int WROWS = BM / 2, WCOLS = BN / 2;
  constexpr int MR = WROWS / 16, NR = WCOLS / 16;
  constexpr int ALOADS = BM / 64, BLOADS = BN / 64;
  constexpr int NLOADS = ALOADS + BLOADS;
  __shared__ __align__(16) ushort Als[DEPTH][BM * 32];
  __shared__ __align__(16) ushort Bls[DEPTH][BN * 32];
  const int tid = threadIdx.x;
  const int lane = tid & 63;
  const int w = tid >> 6;
  const int wr = w >> 1, wc = w & 1;
  const int bid = blockIdx.y * gridDim.x + blockIdx.x;
  const int xcd = bid & 7;
  const int i0 = bid >> 3;
  const int CR = gridDim.x / XR, CC = gridDim.y / XC;
  int rt, ct;
  if constexpr (CTFAST) {
    rt = (xcd % XR) * CR + (i0 / CC);
    ct = (xcd / XR) * CC + (i0 % CC);
  } else {
    rt = (xcd % XR) * CR + (i0 % CR);
    ct = (xcd / XR) * CC + (i0 / CR);
  }
  const int row0 = rt * BM;
  const int col0 = ct * BN;
  const int koff = blockIdx.z * Klen;
  const ushort* Ab = A + (size_t)row0 * K + koff;
  const ushort* Bb = Bw + (size_t)col0 * K + koff;
  const int sr = tid >> 2;
  const int scA = (((tid & 3) ^ ((tid >> 3) & 3)) * 8);
  const int fr = lane & 15;
  const int fg = lane >> 4;
  f32x4 zero = {0.f, 0.f, 0.f, 0.f};
  f32x4 acc[MR][NR];
#pragma unroll
  for (int m = 0; m < MR; m++)
#pragma unroll
    for (int n = 0; n < NR; n++) acc[m][n] = zero;

  auto stage = [&](int slot, int kt) {
#pragma unroll
    for (int i2 = 0; i2 < ALOADS; i2++)
      gload_lds16(Ab + (size_t)(sr + 64 * i2) * K + kt + scA, &Als[slot][i2 * 2048 + tid * 8]);
#pragma unroll
    for (int i2 = 0; i2 < BLOADS; i2++)
      gload_lds16(Bb + (size_t)(sr + 64 * i2) * K + kt + scA, &Bls[slot][i2 * 2048 + tid * 8]);
  };
  const int nt = Klen >> 5;
#pragma unroll
  for (int p = 0; p < DEPTH - 1; p++) stage(p, p << 5);
  int cur = 0, sbuf = DEPTH - 1;
  for (int t = 0; t < nt; t++) {
    const int ahead = nt - 1 - t;
    if constexpr (DEPTH == 3) {
      if (ahead >= 1) asm volatile("s_waitcnt vmcnt(%0)" ::"i"(NLOADS) : "memory");
      else            asm volatile("s_waitcnt vmcnt(0)" ::: "memory");
    } else if constexpr (DEPTH == 4) {
      if (ahead >= 2)      asm volatile("s_waitcnt vmcnt(%0)" ::"i"(2 * NLOADS) : "memory");
      else if (ahead == 1) asm volatile("s_waitcnt vmcnt(%0)" ::"i"(NLOADS) : "memory");
      else                 asm volatile("s_waitcnt vmcnt(0)" ::: "memory");
    } else {
      if (ahead >= 3)      asm volatile("s_waitcnt vmcnt(%0)" ::"i"(3 * NLOADS) : "memory");
      else if (ahead == 2) asm volatile("s_waitcnt vmcnt(%0)" ::"i"(2 * NLOADS) : "memory");
      else if (ahead == 1) asm volatile("s_waitcnt vmcnt(%0)" ::"i"(NLOADS) : "memory");
      else                 asm volatile("s_waitcnt vmcnt(0)" ::: "memory");
    }
    __builtin_amdgcn_s_barrier();
    if (t + DEPTH - 1 < nt) {
      stage(sbuf, (t + DEPTH - 1) << 5);
      sbuf = (sbuf == DEPTH - 1) ? 0 : sbuf + 1;
    }
    bf16x8 af[MR], bfr[NR];
#pragma unroll
    for (int m = 0; m < MR; m++) {
      int rA = wr * WROWS + m * 16 + fr;
      af[m] = *(const bf16x8*)&Als[cur][rA * 32 + ((fg ^ ((rA >> 1) & 3)) << 3)];
    }
#pragma unroll
    for (int n = 0; n < NR; n++) {
      int rB = wc * WCOLS + n * 16 + fr;
      bfr[n] = *(const bf16x8*)&Bls[cur][rB * 32 + ((fg ^ ((rB >> 1) & 3)) << 3)];
    }
#pragma unroll
    for (int m = 0; m < MR; m++)
#pragma unroll
      for (int n = 0; n < NR; n++)
        acc[m][n] = __builtin_amdgcn_mfma_f32_16x16x32_bf16(af[m], bfr[n], acc[m][n], 0, 0, 0);
    cur = (cur == DEPTH - 1) ? 0 : cur + 1;
  }
  const int orow = row0 + wr * WROWS + fg * 4;
  const int ocol = col0 + wc * WCOLS + fr;
  float* Pz = (float*)Cout + (size_t)blockIdx.z * M * N;
#pragma unroll
  for (int m = 0; m < MR; m++) {
#pragma unroll
    for (int j = 0; j < 4; j++) {
      int r = orow + m * 16 + j;
#pragma unroll
      for (int n = 0; n < NR; n++) {
        int cidx = ocol + n * 16;
        size_t idx = (size_t)r * N + cidx;
        float v = acc[m][n][j];
        if (EPI == 0) {
          ((ushort*)Cout)[idx] = f2bf(v);
        } else if (EPI == 1) {
          ((ushort*)Cout)[idx] = f2bf(((const float*)resid)[idx] + v);
        } else if (EPI == 2) {
          ((ushort*)Cout)[idx] = f2bf(gelu_f(v));
        } else if (EPI == 3) {
          ((float*)Cout)[idx] = bf2f(((const ushort*)resid)[idx]) + v;
        } else {
          Pz[idx] = v;
        }
      }
    }
  }
}

// ---------------- split-K reduce: out = bf16resid + P0 + P1 ----------------
__global__ __launch_bounds__(256) void reduce_down_kernel(const float* __restrict__ P0,
                                                          const float* __restrict__ P1,
                                                          const ushort* __restrict__ residb,
                                                          float* __restrict__ out) {
  int i = blockIdx.x * 256 + threadIdx.x;
  float4 a = ((const float4*)P0)[i];
  float4 b = ((const float4*)P1)[i];
  ushort4 r = ((const ushort4*)residb)[i];
  float4 o;
  o.x = a.x + b.x + bf2f(r.x);
  o.y = a.y + b.y + bf2f(r.y);
  o.z = a.z + b.z + bf2f(r.z);
  o.w = a.w + b.w + bf2f(r.w);
  ((float4*)out)[i] = o;
}

// ---------------- RoPE + cosine-sim scaling ----------------
__global__ __launch_bounds__(256) void rope_kernel(const ushort* __restrict__ qkv,
                                                   const float* __restrict__ pos,
                                                   const float* __restrict__ pos_orig,
                                                   const float* __restrict__ timep,
                                                   const float* __restrict__ qk_scale,
                                                   ushort* __restrict__ qr,
                                                   ushort* __restrict__ kr) {
  int gw = (blockIdx.x * 256 + threadIdx.x) >> 6;
  int lane = threadIdx.x & 63;
  int h = gw & 15;
  int row = gw >> 4;
  int b = row >> 11;
  int l = row & (L_ - 1);
  float qv = bf2f(qkv[(size_t)row * 3072 + h * 64 + lane]);
  float kv = bf2f(qkv[(size_t)row * 3072 + 1024 + h * 64 + lane]);
  float c = 1.0f, s = 0.0f;
  if (lane < 50) {
    int idx = lane < 25 ? lane : lane - 25;
    int sg = idx / 5, d = idx % 5;
    int fi = d * 16 + h;
    float th;
    if (sg == 4) {
      th = timep[row] * __expf(-(float)fi * 0.05756462732485115f);
    } else {
      float fr = 3.14159265358979323846f * __expf((float)fi * 0.028782313662425575f);
      const float* psrc = (sg == 0 || sg == 2) ? pos_orig : pos;
      int comp = (sg < 2) ? 1 : 0;
      th = (2.0f * psrc[(size_t)row * 2 + comp] - 1.0f) * fr;
    }
    s = sinf(th);
    c = cosf(th);
  }
  int partner = lane < 25 ? lane + 25 : lane - 25;
  float qp = __shfl(qv, partner, 64);
  float kp = __shfl(kv, partner, 64);
  float yq, yk;
  if (lane < 25) { yq = qv * c - qp * s; yk = kv * c - kp * s; }
  else if (lane < 50) { yq = qv * c + qp * s; yk = kv * c + kp * s; }
  else { yq = qv; yk = kv; }
  float sq = yq * yq, sk = yk * yk;
#pragma unroll
  for (int d = 1; d < 64; d <<= 1) { sq += __shfl_xor(sq, d); sk += __shfl_xor(sk, d); }
  float scl = sqrtf(qk_scale[h]);
  float qo = yq * scl * rsqrtf(sq + 1e-6f);
  float ko = yk * scl * rsqrtf(sk + 1e-6f);
  size_t o = ((size_t)(b * 16 + h) * L_ + l) * 64 + lane;
  qr[o] = f2bf(qo);
  kr[o] = f2bf(ko);
}

// ---------------- V transpose ----------------
__global__ __launch_bounds__(256) void vtrans_kernel(const ushort* __restrict__ qkv,
                                                     ushort* __restrict__ vT) {
  __shared__ __align__(16) ushort tile[64][72];
  int t = threadIdx.x;
  int lt = blockIdx.x;
  int bh = blockIdx.y;
  int b = bh >> 4, h = bh & 15;
  int r = t >> 3, c0 = (t & 7) * 8;
#pragma unroll
  for (int half = 0; half < 2; half++) {
    const ushort* src =
        qkv + (size_t)(b * L_ + lt * 64 + r + half * 32) * 3072 + 2048 + h * 64 + c0;
    *(uint4*)&tile[r + half * 32][c0] = *(const uint4*)src;
  }
  __syncthreads();
#pragma unroll
  for (int half = 0; half < 2; half++) {
    int dh = r + half * 32;
    unsigned p0 = (unsigned)tile[c0 + 0][dh] | ((unsigned)tile[c0 + 1][dh] << 16);
    unsigned p1 = (unsigned)tile[c0 + 2][dh] | ((unsigned)tile[c0 + 3][dh] << 16);
    unsigned p2 = (unsigned)tile[c0 + 4][dh] | ((unsigned)tile[c0 + 5][dh] << 16);
    unsigned p3 = (unsigned)tile[c0 + 6][dh] | ((unsigned)tile[c0 + 7][dh] << 16);
    uint4 o; o.x = p0; o.y = p1; o.z = p2; o.w = p3;
    *(uint4*)&vT[((size_t)bh * 64 + dh) * L_ + lt * 64 + c0] = o;
  }
}

// ---------------- Flash attention: shared K/V fragment loads across both q-sets ------
// LDS-BW was the limiter (36 b128 reads/tile/wave). Now: QK^T for BOTH q-sets inside
// one kf-load loop, softmax to two P buffers, PV for both inside one vb-load loop
// -> 20 b128 reads/tile/wave. Constant-max softmax (cosine-sim bound), row-sum via
// ones-MFMA, XCD-locality remap (4 heads/XCD, K/V L2-resident).
__global__ __launch_bounds__(256) void attn_kernel(const ushort* __restrict__ qr,
                                                   const ushort* __restrict__ kr,
                                                   const ushort* __restrict__ vT,
                                                   ushort* __restrict__ attnb) {
  __shared__ __align__(16) ushort Kls[2][64 * 64];
  __shared__ __align__(16) ushort Vls[2][64 * 64];
  __shared__ __align__(16) ushort Pls[4][2][16 * 64];
  const int tid = threadIdx.x, lane = tid & 63, w = tid >> 6;
  const int bid = blockIdx.x;
  const int qp = (bid >> 3) & 15;
  const int bh = (bid & 7) | ((bid >> 7) << 3);
  const int b = bh >> 4;
  const int fr = lane & 15, fg = lane >> 4;
  const ushort* Qb0 = qr + ((size_t)bh * L_ + qp * 128 + w * 16) * 64;
  const ushort* Qb1 = Qb0 + 64 * 64;
  bf16x8 qf0[2], qf1[2];
#pragma unroll
  for (int c = 0; c < 2; c++) {
    qf0[c] = *(const bf16x8*)(Qb0 + fr * 64 + c * 32 + fg * 8);
    qf1[c] = *(const bf16x8*)(Qb1 + fr * 64 + c * 32 + fg * 8);
  }
  const ushort ob[8] = {0x3F80, 0x3F80, 0x3F80, 0x3F80, 0x3F80, 0x3F80, 0x3F80, 0x3F80};
  const bf16x8 ones = *(const bf16x8*)ob;
  f32x4 zero = {0.f, 0.f, 0.f, 0.f};
  f32x4 accO0[4], accO1[4], acc1_0 = zero, acc1_1 = zero;
#pragma unroll
  for (int n = 0; n < 4; n++) { accO0[n] = zero; accO1[n] = zero; }
  const int sr = tid >> 3;
  const int scz = (((tid & 7) ^ (sr & 7)) * 8);
  auto stage = [&](int buf, int kt) {
    gload_lds16(kr + ((size_t)bh * L_ + kt + sr) * 64 + scz, &Kls[buf][tid * 8]);
    gload_lds16(kr + ((size_t)bh * L_ + kt + 32 + sr) * 64 + scz, &Kls[buf][2048 + tid * 8]);
    gload_lds16(vT + ((size_t)bh * 64 + sr) * L_ + kt + scz, &Vls[buf][tid * 8]);
    gload_lds16(vT + ((size_t)bh * 64 + 32 + sr) * L_ + kt + scz, &Vls[buf][2048 + tid * 8]);
  };
  stage(0, 0);
  int cur = 0;
  for (int t = 0; t < (L_ >> 6); t++) {
    asm volatile("s_waitcnt vmcnt(0)" ::: "memory");
    __builtin_amdgcn_s_barrier();
    __builtin_amdgcn_sched_barrier(0);
    if (t + 1 < (L_ >> 6)) stage(cur ^ 1, (t + 1) << 6);
    // QK^T for both q-sets with SHARED kf loads
    f32x4 sv0[4], sv1[4];
#pragma unroll
    for (int n = 0; n < 4; n++) { sv0[n] = zero; sv1[n] = zero; }
    __builtin_amdgcn_s_setprio(1);
#pragma unroll
    for (int c = 0; c < 2; c++) {
#pragma unroll
      for (int n = 0; n < 4; n++) {
        bf16x8 kf =
            *(const bf16x8*)&Kls[cur][(n * 16 + fr) * 64 + (((c * 4 + fg) ^ (fr & 7)) << 3)];
        sv0[n] = __builtin_amdgcn_mfma_f32_16x16x32_bf16(qf0[c], kf, sv0[n], 0, 0, 0);
        sv1[n] = __builtin_amdgcn_mfma_f32_16x16x32_bf16(qf1[c], kf, sv1[n], 0, 0, 0);
      }
    }
    __builtin_amdgcn_s_setprio(0);
    // softmax both q-sets -> two P buffers
#pragma unroll
    for (int qs = 0; qs < 2; qs++) {
      const f32x4* sv = qs ? sv1 : sv0;
#pragma unroll
      for (int j = 0; j < 4; j++) {
        int row = fg * 4 + j;
        int rbase = row * 64;
        int rx = row & 7;
#pragma unroll
        for (int n = 0; n < 4; n++) {
          float p = __builtin_amdgcn_exp2f(
              fmaf(sv[n][j], 1.4426950408889634f, -17.31234049066756f));
          int chunk = 2 * n + (fr >> 3);
          Pls[w][qs][rbase + ((chunk ^ rx) << 3) + (fr & 7)] =
              (ushort)(__float_as_uint(p) >> 16);
        }
      }
    }
    // PV for both q-sets with SHARED vb loads
    __builtin_amdgcn_s_setprio(1);
#pragma unroll
    for (int c = 0; c < 2; c++) {
      bf16x8 pa0 = *(const bf16x8*)&Pls[w][0][fr * 64 + (((c * 4 + fg) ^ (fr & 7)) << 3)];
      bf16x8 pa1 = *(const bf16x8*)&Pls[w][1][fr * 64 + (((c * 4 + fg) ^ (fr & 7)) << 3)];
#pragma unroll
      for (int n = 0; n < 4; n++) {
        bf16x8 vb =
            *(const bf16x8*)&Vls[cur][(n * 16 + fr) * 64 + (((c * 4 + fg) ^ (fr & 7)) << 3)];
        accO0[n] = __builtin_amdgcn_mfma_f32_16x16x32_bf16(pa0, vb, accO0[n], 0, 0, 0);
        accO1[n] = __builtin_amdgcn_mfma_f32_16x16x32_bf16(pa1, vb, accO1[n], 0, 0, 0);
      }
      acc1_0 = __builtin_amdgcn_mfma_f32_16x16x32_bf16(pa0, ones, acc1_0, 0, 0, 0);
      acc1_1 = __builtin_amdgcn_mfma_f32_16x16x32_bf16(pa1, ones, acc1_1, 0, 0, 0);
    }
    __builtin_amdgcn_s_setprio(0);
    cur ^= 1;
  }
#pragma unroll
  for (int qs = 0; qs < 2; qs++) {
    const f32x4* accO = qs ? accO1 : accO0;
    const f32x4& acc1 = qs ? acc1_1 : acc1_0;
    float inv[4];
#pragma unroll
    for (int j = 0; j < 4; j++) inv[j] = 1.0f / acc1[j];
#pragma unroll
    for (int n = 0; n < 4; n++) {
#pragma unroll
      for (int j = 0; j < 4; j++) {
        float o = accO[n][j] * inv[j];
        int qrow = qp * 128 + qs * 64 + w * 16 + fg * 4 + j;
        int dh = fr + n * 16;
        attnb[(size_t)(b * L_ + qrow) * 1024 + (bh & 15) * 64 + dh] = f2bf(o);
      }
    }
  }
}

extern "C" void kernel_launch(void* const* d_in, const int* in_sizes, int n_in,
                              void* d_out, int out_size, void* d_ws, size_t ws_size,
                              hipStream_t stream) {
  const float* x = (const float*)d_in[0];
  const float* pos = (const float*)d_in[1];
  const float* pos_orig = (const float*)d_in[2];
  const float* timep = (const float*)d_in[3];
  const float* w_qkv = (const float*)d_in[4];
  const float* w_out = (const float*)d_in[5];
  const float* w_up = (const float*)d_in[6];
  const float* w_down = (const float*)d_in[7];
  const float* norm1 = (const float*)d_in[8];
  const float* norm2 = (const float*)d_in[9];
  const float* qk_scale = (const float*)d_in[10];
  float* out = (float*)d_out;
  char* ws = (char*)d_ws;
  size_t off = 0;
  auto alloc = [&](size_t bytes) {
    void* p = ws + off;
    off += bytes;
    return p;
  };
  ushort* xn = (ushort*)alloc(8ull << 20);
  ushort* qkvb = (ushort*)alloc(32ull << 20);
  ushort* qrb = (ushort*)alloc(8ull << 20);
  ushort* krb = (ushort*)alloc(8ull << 20);
  ushort* vTb = (ushort*)alloc(8ull << 20);
  ushort* attnb = (ushort*)alloc(8ull << 20);
  ushort* x1b = (ushort*)alloc(8ull << 20);
  ushort* wqkvb = (ushort*)alloc(6ull << 20);
  ushort* woutb = (ushort*)alloc(2ull << 20);
  ushort* wupb = (ushort*)alloc(8ull << 20);
  ushort* wdownb = (ushort*)alloc(8ull << 20);
  float* Ppart = (float*)qrb;

  cast_all_kernel<<<12288, 256, 0, stream>>>(w_qkv, w_out, w_up, w_down,
                                             wqkvb, woutb, wupb, wdownb);

  rmsnorm_kernel<float><<<4096, 256, 0, stream>>>(x, norm1, xn);
  gemm256<0, 4, 2><<<dim3(16, 12), 512, 0, stream>>>(xn, wqkvb, qkvb, 4096, 3072, 1024);
  rope_kernel<<<16384, 256, 0, stream>>>(qkvb, pos, pos_orig, timep, qk_scale, qrb, krb);
  vtrans_kernel<<<dim3(32, 32), 256, 0, stream>>>(qkvb, vTb);
  attn_kernel<<<512, 256, 0, stream>>>(qrb, krb, vTb, attnb);
  gemm_nt<1, 64, 64, 5, 4, 2, false><<<dim3(64, 16), 256, 0, stream>>>(
      attnb, woutb, x1b, x, 4096, 1024, 1024, 1024);
  rmsnorm_kernel<ushort><<<4096, 256, 0, stream>>>(x1b, norm2, xn);
  gemm256<2, 4, 2><<<dim3(16, 16), 512, 0, stream>>>(xn, wupb, qkvb, 4096, 4096, 1024);
  gemm_nt<4, 128, 128, 4, 4, 2, true><<<dim3(32, 8, 2), 256, 0, stream>>>(
      qkvb, wdownb, Ppart, nullptr, 4096, 1024, 4096, 2048);
  reduce_down_kernel<<<4096, 256, 0, stream>>>(Ppart, Ppart + (4u << 20), x1b, out);
}